// Round 1
// baseline (397.275 us; speedup 1.0000x reference)
//
#include <hip/hip_runtime.h>
#include <hip/hip_bf16.h>
#include <stdint.h>

#define T_SEQ 2048
#define HS    2048
#define NH    16
#define DH    128
#define QKVN  (3*HS)

typedef __attribute__((ext_vector_type(8))) short          bf16x8;
typedef __attribute__((ext_vector_type(4))) float          f32x4;
typedef __attribute__((ext_vector_type(4))) unsigned short us4;
typedef __attribute__((ext_vector_type(8))) unsigned short us8;

// round-to-nearest-even f32 -> bf16 bits
__device__ __forceinline__ unsigned short f2bf(float x) {
  unsigned int u = __float_as_uint(x);
  return (unsigned short)((u + 0x7fffu + ((u >> 16) & 1u)) >> 16);
}

// async global->LDS, 16B per lane; lds base must be wave-uniform (lane i lands at base + i*16B)
__device__ __forceinline__ void gl_lds16(const void* g, void* l) {
  __builtin_amdgcn_global_load_lds((__attribute__((address_space(1))) void*)g,
                                   (__attribute__((address_space(3))) void*)l, 16, 0, 0);
}

// ---------------- elementwise cast f32 -> bf16 (vectorized 8/thread) ----------------
__global__ __launch_bounds__(256) void cast_bf16_kernel(const float* __restrict__ in,
                                                        unsigned short* __restrict__ out, int n) {
  int i = (blockIdx.x * 256 + threadIdx.x) * 8;
  if (i >= n) return;
  f32x4 a = *(const f32x4*)(in + i);
  f32x4 b = *(const f32x4*)(in + i + 4);
  us8 r;
#pragma unroll
  for (int j = 0; j < 4; ++j) { r[j] = f2bf(a[j]); r[j + 4] = f2bf(b[j]); }
  *(us8*)(out + i) = r;
}

// ---------------- RoPE cos/sin table [T][64] ----------------
__global__ __launch_bounds__(256) void rope_table_kernel(float* __restrict__ cosd,
                                                         float* __restrict__ sind) {
  int i = blockIdx.x * 256 + threadIdx.x;   // over T*64
  if (i >= T_SEQ * 64) return;
  int t = i >> 6, f = i & 63;
  // inv_freq = 10000^(-f/64) ; precise expf to match jnp closely
  float inv = expf(-9.210340371976184f * (float)f * (1.0f / 64.0f));
  float ang = (float)t * inv;
  float s, c;
  sincosf(ang, &s, &c);
  cosd[i] = c; sind[i] = s;
}

// ---------------- GEMM C[M][N] = A[M][K](bf16) * Bt[N][K](bf16)^T (+bias) ----------------
// 128x128 tile, BK=64, 256 threads (4 waves, each 64x64 out), mfma_f32_16x16x32_bf16
template <int BIAS>
__global__ __launch_bounds__(256, 2)
void gemm_bt(const unsigned short* __restrict__ A, const unsigned short* __restrict__ Bt,
             float* __restrict__ C, const float* __restrict__ bias, int M, int N, int K) {
  __shared__ unsigned short As[128 * 64];
  __shared__ unsigned short Bs[128 * 64];
  const int tid  = threadIdx.x;
  const int lane = tid & 63;
  const int w    = tid >> 6;
  const int fr   = lane & 15;   // fragment row/col
  const int fq   = lane >> 4;   // k-group
  const int bm   = blockIdx.y * 128;
  const int bn   = blockIdx.x * 128;
  const int wr   = (w >> 1) * 64;
  const int wc   = (w & 1) * 64;

  f32x4 acc[4][4];
#pragma unroll
  for (int m = 0; m < 4; ++m)
#pragma unroll
    for (int n = 0; n < 4; ++n) { acc[m][n][0]=0.f; acc[m][n][1]=0.f; acc[m][n][2]=0.f; acc[m][n][3]=0.f; }

  const int srow = lane >> 3;        // 8 rows per load-instr (128B rows)
  const int scol = (lane & 7) * 8;   // element offset within row
  const unsigned short* Ag = A + (long)bm * K;
  const unsigned short* Bg = Bt + (long)bn * K;

  const int nk = K >> 6;
  for (int kt = 0; kt < nk; ++kt) {
    const int k0 = kt << 6;
    __syncthreads();               // previous compute done, LDS free
#pragma unroll
    for (int i = 0; i < 4; ++i) {
      int r = i * 32 + w * 8;      // wave-uniform chunk base row
      gl_lds16(Ag + (long)(r + srow) * K + k0 + scol, &As[r * 64]);
      gl_lds16(Bg + (long)(r + srow) * K + k0 + scol, &Bs[r * 64]);
    }
    __syncthreads();               // drains vmcnt(0): tiles resident
#pragma unroll
    for (int ks = 0; ks < 2; ++ks) {
      bf16x8 af[4], bfr[4];
#pragma unroll
      for (int m = 0; m < 4; ++m) af[m]  = *(const bf16x8*)&As[(wr + m * 16 + fr) * 64 + ks * 32 + fq * 8];
#pragma unroll
      for (int n = 0; n < 4; ++n) bfr[n] = *(const bf16x8*)&Bs[(wc + n * 16 + fr) * 64 + ks * 32 + fq * 8];
#pragma unroll
      for (int m = 0; m < 4; ++m)
#pragma unroll
        for (int n = 0; n < 4; ++n)
          acc[m][n] = __builtin_amdgcn_mfma_f32_16x16x32_bf16(af[m], bfr[n], acc[m][n], 0, 0, 0);
    }
  }
  // epilogue: C/D layout col=lane&15, row=(lane>>4)*4+reg
#pragma unroll
  for (int m = 0; m < 4; ++m) {
    int row0 = bm + wr + m * 16 + fq * 4;
#pragma unroll
    for (int n = 0; n < 4; ++n) {
      int col = bn + wc + n * 16 + fr;
      float bv = BIAS ? bias[col] : 0.0f;
#pragma unroll
      for (int j = 0; j < 4; ++j)
        C[(long)(row0 + j) * N + col] = acc[m][n][j] + bv;
    }
  }
}

// ---------------- fused RMSNorm + RoPE for q,k; writes bf16 [h][t][d] ----------------
__global__ __launch_bounds__(128)
void normrope_qk(const float* __restrict__ qkv, const float* __restrict__ cosd,
                 const float* __restrict__ sind, unsigned short* __restrict__ qb,
                 unsigned short* __restrict__ kb) {
  const int t = blockIdx.x;
  const int y = blockIdx.y;          // 0..31 : q heads then k heads
  const int kind = y >> 4;
  const int h = y & 15;
  const int d = threadIdx.x;         // 0..127
  float x = qkv[(long)t * QKVN + y * 128 + d];
  float ss = x * x;
#pragma unroll
  for (int m = 1; m < 64; m <<= 1) ss += __shfl_xor(ss, m, 64);
  __shared__ float red[2];
  __shared__ float xn[128];
  if ((d & 63) == 0) red[d >> 6] = ss;
  __syncthreads();
  ss = red[0] + red[1];
  float r = rsqrtf(ss * (1.0f / 128.0f) + 1.1920928955078125e-07f);
  float v = x * r;
  xn[d] = v;
  __syncthreads();
  float o;
  if (d < 64) {
    float c = cosd[t * 64 + d], s = sind[t * 64 + d];
    o = v * c + xn[d + 64] * s;
  } else {
    float c = cosd[t * 64 + d - 64], s = sind[t * 64 + d - 64];
    o = -xn[d - 64] * s + v * c;
  }
  unsigned short* dst = kind ? kb : qb;
  dst[((long)h * T_SEQ + t) * 128 + d] = f2bf(o);
}

// ---------------- V: cast + transpose to [h][d][t] bf16 ----------------
__global__ __launch_bounds__(256)
void v_transpose(const float* __restrict__ qkv, unsigned short* __restrict__ vt) {
  const int tb = blockIdx.x;   // 64-row t tile
  const int h  = blockIdx.y;
  __shared__ unsigned short vl[128][72];   // pad: row stride 144B (16B aligned)
  const int tid = threadIdx.x;
#pragma unroll
  for (int p = 0; p < 32; ++p) {
    int rr = p * 2 + (tid >> 7);
    int d  = tid & 127;
    float x = qkv[(long)(tb * 64 + rr) * QKVN + 2 * HS + h * 128 + d];
    vl[d][rr] = f2bf(x);
  }
  __syncthreads();
#pragma unroll
  for (int p = 0; p < 8; ++p) {
    int idx = (p * 256 + tid) * 4;   // elem in [128][64]
    int d = idx >> 6;
    int i = idx & 63;
    us4 val = *(const us4*)&vl[d][i];
    *(us4*)&vt[((long)h * DH + d) * T_SEQ + tb * 64 + i] = val;
  }
}

// ---------------- causal flash attention ----------------
// grid (T/64, NH), 256 thr (4 waves); wave w owns q rows [qb*64+w*16, +16)
__global__ __launch_bounds__(256, 2)
void attn_kernel(const unsigned short* __restrict__ qg, const unsigned short* __restrict__ kg,
                 const unsigned short* __restrict__ vtg, unsigned short* __restrict__ yb) {
  const int qb = blockIdx.x;
  const int h  = blockIdx.y;
  __shared__ unsigned short Qs[64 * 128];
  __shared__ unsigned short Ks[64 * 128];
  __shared__ unsigned short Vts[128 * 64];
  __shared__ unsigned short Ps[4][16 * 72];   // per-wave P tile, padded rows (144B)

  const int tid = threadIdx.x, lane = tid & 63, w = tid >> 6;
  const int fr = lane & 15, fq = lane >> 4;

  const unsigned short* qh = qg  + (long)h * T_SEQ * 128;
  const unsigned short* kh = kg  + (long)h * T_SEQ * 128;
  const unsigned short* vh = vtg + (long)h * 128 * T_SEQ;

  // stage Q tile (contiguous 16KB)
  {
    const unsigned short* src = qh + qb * 64 * 128;
#pragma unroll
    for (int i = 0; i < 4; ++i) {
      int c = w * 4 + i;
      gl_lds16(src + c * 512 + lane * 8, &Qs[c * 512]);
    }
  }
  __syncthreads();
  bf16x8 aq[4];
#pragma unroll
  for (int ks = 0; ks < 4; ++ks)
    aq[ks] = *(const bf16x8*)&Qs[(w * 16 + fr) * 128 + ks * 32 + fq * 8];

  f32x4 acc[8];
#pragma unroll
  for (int n = 0; n < 8; ++n) { acc[n][0]=0.f; acc[n][1]=0.f; acc[n][2]=0.f; acc[n][3]=0.f; }
  float mrow[4], lrow[4];
#pragma unroll
  for (int j = 0; j < 4; ++j) { mrow[j] = -__builtin_huge_valf(); lrow[j] = 0.f; }

  const float scale = 0.08838834764831845f;   // 1/sqrt(128)

  for (int kt = 0; kt <= qb; ++kt) {
    __syncthreads();   // previous tile's reads done before restage
    const unsigned short* ksrc = kh + kt * 64 * 128;
#pragma unroll
    for (int i = 0; i < 4; ++i) {
      int c = w * 4 + i;
      gl_lds16(ksrc + c * 512 + lane * 8, &Ks[c * 512]);
    }
#pragma unroll
    for (int i = 0; i < 4; ++i) {
      int r0 = (w * 4 + i) * 8;
      gl_lds16(vh + (long)(r0 + (lane >> 3)) * T_SEQ + kt * 64 + (lane & 7) * 8, &Vts[r0 * 64]);
    }
    __syncthreads();

    // S = Q K^T (16 x 64 per wave)
    f32x4 sv[4];
#pragma unroll
    for (int n = 0; n < 4; ++n) { sv[n][0]=0.f; sv[n][1]=0.f; sv[n][2]=0.f; sv[n][3]=0.f; }
#pragma unroll
    for (int ks = 0; ks < 4; ++ks)
#pragma unroll
      for (int n = 0; n < 4; ++n) {
        bf16x8 bk = *(const bf16x8*)&Ks[(n * 16 + fr) * 128 + ks * 32 + fq * 8];
        sv[n] = __builtin_amdgcn_mfma_f32_16x16x32_bf16(aq[ks], bk, sv[n], 0, 0, 0);
      }

    // scale + causal mask (only diagonal tile can mask)
#pragma unroll
    for (int n = 0; n < 4; ++n)
#pragma unroll
      for (int j = 0; j < 4; ++j) {
        float s = sv[n][j] * scale;
        if (kt == qb && (n * 16 + fr) > (w * 16 + fq * 4 + j)) s = -__builtin_huge_valf();
        sv[n][j] = s;
      }

    // row max over 64 cols: local over n, then 16-lane butterfly
    float pm[4];
#pragma unroll
    for (int j = 0; j < 4; ++j)
      pm[j] = fmaxf(fmaxf(sv[0][j], sv[1][j]), fmaxf(sv[2][j], sv[3][j]));
#pragma unroll
    for (int m = 1; m < 16; m <<= 1)
#pragma unroll
      for (int j = 0; j < 4; ++j) pm[j] = fmaxf(pm[j], __shfl_xor(pm[j], m, 64));

    float alpha[4];
#pragma unroll
    for (int j = 0; j < 4; ++j) {
      float mn = fmaxf(mrow[j], pm[j]);
      alpha[j] = __expf(mrow[j] - mn);   // exp(-inf)=0 on first tile
      mrow[j] = mn;
    }
    float rs[4] = {0.f, 0.f, 0.f, 0.f};
#pragma unroll
    for (int n = 0; n < 4; ++n)
#pragma unroll
      for (int j = 0; j < 4; ++j) {
        float p = __expf(sv[n][j] - mrow[j]);
        sv[n][j] = p;
        rs[j] += p;
      }
#pragma unroll
    for (int m = 1; m < 16; m <<= 1)
#pragma unroll
      for (int j = 0; j < 4; ++j) rs[j] += __shfl_xor(rs[j], m, 64);
#pragma unroll
    for (int j = 0; j < 4; ++j) lrow[j] = lrow[j] * alpha[j] + rs[j];
#pragma unroll
    for (int n = 0; n < 8; ++n)
#pragma unroll
      for (int j = 0; j < 4; ++j) acc[n][j] *= alpha[j];

    // P -> per-wave LDS (bf16), then read as PV A-fragments
    unsigned short* pl = &Ps[w][0];
#pragma unroll
    for (int n = 0; n < 4; ++n)
#pragma unroll
      for (int j = 0; j < 4; ++j)
        pl[(fq * 4 + j) * 72 + n * 16 + fr] = f2bf(sv[n][j]);
    asm volatile("s_waitcnt lgkmcnt(0)" ::: "memory");
#pragma unroll
    for (int ks = 0; ks < 2; ++ks) {
      bf16x8 pa = *(const bf16x8*)&pl[fr * 72 + ks * 32 + fq * 8];
#pragma unroll
      for (int n = 0; n < 8; ++n) {
        bf16x8 bv = *(const bf16x8*)&Vts[(n * 16 + fr) * 64 + ks * 32 + fq * 8];
        acc[n] = __builtin_amdgcn_mfma_f32_16x16x32_bf16(pa, bv, acc[n], 0, 0, 0);
      }
    }
  }

  // epilogue: y[t][h*128+d] bf16
#pragma unroll
  for (int j = 0; j < 4; ++j) {
    float inv = 1.0f / lrow[j];
    int t = qb * 64 + w * 16 + fq * 4 + j;
#pragma unroll
    for (int n = 0; n < 8; ++n)
      yb[(long)t * HS + h * 128 + n * 16 + fr] = f2bf(acc[n][j] * inv);
  }
}

// ---------------- launch ----------------
extern "C" void kernel_launch(void* const* d_in, const int* in_sizes, int n_in,
                              void* d_out, int out_size, void* d_ws, size_t ws_size,
                              hipStream_t stream) {
  const float* x    = (const float*)d_in[0];
  const float* Wqkv = (const float*)d_in[1];
  const float* Wo_w = (const float*)d_in[2];
  const float* Wo_b = (const float*)d_in[3];
  float* out = (float*)d_out;
  char* ws = (char*)d_ws;

  unsigned short* xbf  = (unsigned short*)(ws + 0L);          //  8.0 MB
  unsigned short* wqbf = (unsigned short*)(ws + 8388608L);    // 24.0 MB
  unsigned short* wobf = (unsigned short*)(ws + 33554432L);   //  8.0 MB
  float*          qkv  = (float*)         (ws + 41943040L);   // 48.0 MB
  unsigned short* qb   = (unsigned short*)(ws + 92274688L);   //  8.0 MB
  unsigned short* kb   = (unsigned short*)(ws + 100663296L);  //  8.0 MB
  unsigned short* vt   = (unsigned short*)(ws + 109051904L);  //  8.0 MB
  unsigned short* yb   = (unsigned short*)(ws + 117440512L);  //  8.0 MB
  float*          cosd = (float*)         (ws + 125829120L);  //  0.5 MB
  float*          sind = (float*)         (ws + 126353408L);  //  0.5 MB

  cast_bf16_kernel<<<dim3(4194304 / 8 / 256), 256, 0, stream>>>(x, xbf, 4194304);
  cast_bf16_kernel<<<dim3(12582912 / 8 / 256), 256, 0, stream>>>(Wqkv, wqbf, 12582912);
  cast_bf16_kernel<<<dim3(4194304 / 8 / 256), 256, 0, stream>>>(Wo_w, wobf, 4194304);
  rope_table_kernel<<<dim3(512), 256, 0, stream>>>(cosd, sind);

  gemm_bt<0><<<dim3(QKVN / 128, T_SEQ / 128), 256, 0, stream>>>(xbf, wqbf, qkv, nullptr,
                                                                T_SEQ, QKVN, HS);
  normrope_qk<<<dim3(T_SEQ, 2 * NH), 128, 0, stream>>>(qkv, cosd, sind, qb, kb);
  v_transpose<<<dim3(T_SEQ / 64, NH), 256, 0, stream>>>(qkv, vt);
  attn_kernel<<<dim3(T_SEQ / 64, NH), 256, 0, stream>>>(qb, kb, vt, yb);
  gemm_bt<1><<<dim3(HS / 128, T_SEQ / 128), 256, 0, stream>>>(yb, wobf, out, Wo_b,
                                                              T_SEQ, HS, HS);
}

// Round 3
// 350.033 us; speedup vs baseline: 1.1350x; 1.1350x over previous
//
#include <hip/hip_runtime.h>
#include <hip/hip_bf16.h>
#include <stdint.h>

#define T_SEQ 2048
#define HS    2048
#define NH    16
#define DH    128
#define QKVN  (3*HS)

typedef __attribute__((ext_vector_type(8))) short          bf16x8;
typedef __attribute__((ext_vector_type(4))) float          f32x4;
typedef __attribute__((ext_vector_type(4))) unsigned short us4;
typedef __attribute__((ext_vector_type(8))) unsigned short us8;

// round-to-nearest-even f32 -> bf16 bits
__device__ __forceinline__ unsigned short f2bf(float x) {
  unsigned int u = __float_as_uint(x);
  return (unsigned short)((u + 0x7fffu + ((u >> 16) & 1u)) >> 16);
}

// async global->LDS, 16B per lane; lds base must be wave-uniform (lane i lands at base + i*16B)
__device__ __forceinline__ void gl_lds16(const void* g, void* l) {
  __builtin_amdgcn_global_load_lds((__attribute__((address_space(1))) void*)g,
                                   (__attribute__((address_space(3))) void*)l, 16, 0, 0);
}

// ---------------- elementwise cast f32 -> bf16 (vectorized 8/thread) ----------------
__global__ __launch_bounds__(256) void cast_bf16_kernel(const float* __restrict__ in,
                                                        unsigned short* __restrict__ out, int n) {
  int i = (blockIdx.x * 256 + threadIdx.x) * 8;
  if (i >= n) return;
  f32x4 a = *(const f32x4*)(in + i);
  f32x4 b = *(const f32x4*)(in + i + 4);
  us8 r;
#pragma unroll
  for (int j = 0; j < 4; ++j) { r[j] = f2bf(a[j]); r[j + 4] = f2bf(b[j]); }
  *(us8*)(out + i) = r;
}

// ---------------- RoPE cos/sin table [T][64] ----------------
__global__ __launch_bounds__(256) void rope_table_kernel(float* __restrict__ cosd,
                                                         float* __restrict__ sind) {
  int i = blockIdx.x * 256 + threadIdx.x;   // over T*64
  if (i >= T_SEQ * 64) return;
  int t = i >> 6, f = i & 63;
  // inv_freq = 10000^(-f/64) ; precise expf to match jnp closely
  float inv = expf(-9.210340371976184f * (float)f * (1.0f / 64.0f));
  float ang = (float)t * inv;
  float s, c;
  sincosf(ang, &s, &c);
  cosd[i] = c; sind[i] = s;
}

// ---------------- GEMM C[M][N] = A[M][K](bf16) * Bt[N][K](bf16)^T (+bias) ----------------
// 128x128 tile, BK=64, 256 threads (4 waves, each 64x64 out), mfma_f32_16x16x32_bf16
template <int BIAS>
__global__ __launch_bounds__(256, 2)
void gemm_bt(const unsigned short* __restrict__ A, const unsigned short* __restrict__ Bt,
             float* __restrict__ C, const float* __restrict__ bias, int M, int N, int K) {
  __shared__ unsigned short As[128 * 64];
  __shared__ unsigned short Bs[128 * 64];
  const int tid  = threadIdx.x;
  const int lane = tid & 63;
  const int w    = tid >> 6;
  const int fr   = lane & 15;   // fragment row/col
  const int fq   = lane >> 4;   // k-group
  const int bm   = blockIdx.y * 128;
  const int bn   = blockIdx.x * 128;
  const int wr   = (w >> 1) * 64;
  const int wc   = (w & 1) * 64;

  f32x4 acc[4][4];
#pragma unroll
  for (int m = 0; m < 4; ++m)
#pragma unroll
    for (int n = 0; n < 4; ++n) { acc[m][n][0]=0.f; acc[m][n][1]=0.f; acc[m][n][2]=0.f; acc[m][n][3]=0.f; }

  const int srow = lane >> 3;        // 8 rows per load-instr (128B rows)
  const int scol = (lane & 7) * 8;   // element offset within row
  const unsigned short* Ag = A + (long)bm * K;
  const unsigned short* Bg = Bt + (long)bn * K;

  const int nk = K >> 6;
  for (int kt = 0; kt < nk; ++kt) {
    const int k0 = kt << 6;
    __syncthreads();               // previous compute done, LDS free
#pragma unroll
    for (int i = 0; i < 4; ++i) {
      int r = i * 32 + w * 8;      // wave-uniform chunk base row
      gl_lds16(Ag + (long)(r + srow) * K + k0 + scol, &As[r * 64]);
      gl_lds16(Bg + (long)(r + srow) * K + k0 + scol, &Bs[r * 64]);
    }
    __syncthreads();               // drains vmcnt(0): tiles resident
#pragma unroll
    for (int ks = 0; ks < 2; ++ks) {
      bf16x8 af[4], bfr[4];
#pragma unroll
      for (int m = 0; m < 4; ++m) af[m]  = *(const bf16x8*)&As[(wr + m * 16 + fr) * 64 + ks * 32 + fq * 8];
#pragma unroll
      for (int n = 0; n < 4; ++n) bfr[n] = *(const bf16x8*)&Bs[(wc + n * 16 + fr) * 64 + ks * 32 + fq * 8];
#pragma unroll
      for (int m = 0; m < 4; ++m)
#pragma unroll
        for (int n = 0; n < 4; ++n)
          acc[m][n] = __builtin_amdgcn_mfma_f32_16x16x32_bf16(af[m], bfr[n], acc[m][n], 0, 0, 0);
    }
  }
  // epilogue: C/D layout col=lane&15, row=(lane>>4)*4+reg
#pragma unroll
  for (int m = 0; m < 4; ++m) {
    int row0 = bm + wr + m * 16 + fq * 4;
#pragma unroll
    for (int n = 0; n < 4; ++n) {
      int col = bn + wc + n * 16 + fr;
      float bv = BIAS ? bias[col] : 0.0f;
#pragma unroll
      for (int j = 0; j < 4; ++j)
        C[(long)(row0 + j) * N + col] = acc[m][n][j] + bv;
    }
  }
}

// ---------------- fused RMSNorm + RoPE for q,k; writes bf16 [h][t][d] ----------------
__global__ __launch_bounds__(128)
void normrope_qk(const float* __restrict__ qkv, const float* __restrict__ cosd,
                 const float* __restrict__ sind, unsigned short* __restrict__ qb,
                 unsigned short* __restrict__ kb) {
  const int t = blockIdx.x;
  const int y = blockIdx.y;          // 0..31 : q heads then k heads
  const int kind = y >> 4;
  const int h = y & 15;
  const int d = threadIdx.x;         // 0..127
  float x = qkv[(long)t * QKVN + y * 128 + d];
  float ss = x * x;
#pragma unroll
  for (int m = 1; m < 64; m <<= 1) ss += __shfl_xor(ss, m, 64);
  __shared__ float red[2];
  __shared__ float xn[128];
  if ((d & 63) == 0) red[d >> 6] = ss;
  __syncthreads();
  ss = red[0] + red[1];
  float r = rsqrtf(ss * (1.0f / 128.0f) + 1.1920928955078125e-07f);
  float v = x * r;
  xn[d] = v;
  __syncthreads();
  float o;
  if (d < 64) {
    float c = cosd[t * 64 + d], s = sind[t * 64 + d];
    o = v * c + xn[d + 64] * s;
  } else {
    float c = cosd[t * 64 + d - 64], s = sind[t * 64 + d - 64];
    o = -xn[d - 64] * s + v * c;
  }
  unsigned short* dst = kind ? kb : qb;
  dst[((long)h * T_SEQ + t) * 128 + d] = f2bf(o);
}

// ---------------- V: cast + transpose to [h][d][t] bf16 ----------------
__global__ __launch_bounds__(256)
void v_transpose(const float* __restrict__ qkv, unsigned short* __restrict__ vt) {
  const int tb = blockIdx.x;   // 64-row t tile
  const int h  = blockIdx.y;
  __shared__ unsigned short vl[128][72];   // pad: row stride 144B (16B aligned)
  const int tid = threadIdx.x;
#pragma unroll
  for (int p = 0; p < 32; ++p) {
    int rr = p * 2 + (tid >> 7);
    int d  = tid & 127;
    float x = qkv[(long)(tb * 64 + rr) * QKVN + 2 * HS + h * 128 + d];
    vl[d][rr] = f2bf(x);
  }
  __syncthreads();
#pragma unroll
  for (int p = 0; p < 8; ++p) {
    int idx = (p * 256 + tid) * 4;   // elem in [128][64]
    int d = idx >> 6;
    int i = idx & 63;
    us4 val = *(const us4*)&vl[d][i];
    *(us4*)&vt[((long)h * DH + d) * T_SEQ + tb * 64 + i] = val;
  }
}

// ---------------- causal flash attention ----------------
// 1D grid of 512 blocks; balanced (qb,h) remap so co-resident blocks i and
// i+256 have complementary causal work (31-q0 and q0 -> 33 tiles per CU pair),
// long blocks dispatched first. 256 thr (4 waves); wave w owns 16 q rows.
__global__ __launch_bounds__(256, 3)
void attn_kernel(const unsigned short* __restrict__ qg, const unsigned short* __restrict__ kg,
                 const unsigned short* __restrict__ vtg, unsigned short* __restrict__ yb) {
  const int bi = blockIdx.x;
  const int j  = (bi < 256) ? bi : bi - 256;
  const int h  = j & 15;
  const int q0 = j >> 4;                       // 0..15
  const int qb = (bi < 256) ? (31 - q0) : q0;  // first half long, second half short

  __shared__ unsigned short Ks[64 * 128];
  __shared__ unsigned short Vts[128 * 64];
  __shared__ unsigned short Ps[4][16 * 72];   // per-wave P tile, padded rows (144B)

  const int tid = threadIdx.x, lane = tid & 63, w = tid >> 6;
  const int fr = lane & 15, fq = lane >> 4;

  const unsigned short* qh = qg  + (long)h * T_SEQ * 128;
  const unsigned short* kh = kg  + (long)h * T_SEQ * 128;
  const unsigned short* vh = vtg + (long)h * 128 * T_SEQ;

  // Q fragments straight from global (read once, no LDS round-trip)
  bf16x8 aq[4];
  {
    const unsigned short* qrow = qh + (long)(qb * 64 + w * 16 + fr) * 128;
#pragma unroll
    for (int ks = 0; ks < 4; ++ks)
      aq[ks] = *(const bf16x8*)(qrow + ks * 32 + fq * 8);
  }

  f32x4 acc[8];
#pragma unroll
  for (int n = 0; n < 8; ++n) { acc[n][0]=0.f; acc[n][1]=0.f; acc[n][2]=0.f; acc[n][3]=0.f; }
  float mrow[4], lrow[4];
#pragma unroll
  for (int j2 = 0; j2 < 4; ++j2) { mrow[j2] = -__builtin_huge_valf(); lrow[j2] = 0.f; }

  const float scale = 0.08838834764831845f;   // 1/sqrt(128)

  for (int kt = 0; kt <= qb; ++kt) {
    __syncthreads();   // previous tile's reads done before restage
    const unsigned short* ksrc = kh + kt * 64 * 128;
#pragma unroll
    for (int i = 0; i < 4; ++i) {
      int c = w * 4 + i;
      gl_lds16(ksrc + c * 512 + lane * 8, &Ks[c * 512]);
    }
#pragma unroll
    for (int i = 0; i < 4; ++i) {
      int r0 = (w * 4 + i) * 8;
      gl_lds16(vh + (long)(r0 + (lane >> 3)) * T_SEQ + kt * 64 + (lane & 7) * 8, &Vts[r0 * 64]);
    }
    __syncthreads();

    // S = Q K^T (16 x 64 per wave)
    f32x4 sv[4];
#pragma unroll
    for (int n = 0; n < 4; ++n) { sv[n][0]=0.f; sv[n][1]=0.f; sv[n][2]=0.f; sv[n][3]=0.f; }
#pragma unroll
    for (int ks = 0; ks < 4; ++ks)
#pragma unroll
      for (int n = 0; n < 4; ++n) {
        bf16x8 bk = *(const bf16x8*)&Ks[(n * 16 + fr) * 128 + ks * 32 + fq * 8];
        sv[n] = __builtin_amdgcn_mfma_f32_16x16x32_bf16(aq[ks], bk, sv[n], 0, 0, 0);
      }

    // scale + causal mask (only diagonal tile can mask)
#pragma unroll
    for (int n = 0; n < 4; ++n)
#pragma unroll
      for (int j3 = 0; j3 < 4; ++j3) {
        float s = sv[n][j3] * scale;
        if (kt == qb && (n * 16 + fr) > (w * 16 + fq * 4 + j3)) s = -__builtin_huge_valf();
        sv[n][j3] = s;
      }

    // row max over 64 cols: local over n, then 16-lane butterfly
    float pm[4];
#pragma unroll
    for (int j3 = 0; j3 < 4; ++j3)
      pm[j3] = fmaxf(fmaxf(sv[0][j3], sv[1][j3]), fmaxf(sv[2][j3], sv[3][j3]));
#pragma unroll
    for (int m = 1; m < 16; m <<= 1)
#pragma unroll
      for (int j3 = 0; j3 < 4; ++j3) pm[j3] = fmaxf(pm[j3], __shfl_xor(pm[j3], m, 64));

    float alpha[4];
#pragma unroll
    for (int j3 = 0; j3 < 4; ++j3) {
      float mn = fmaxf(mrow[j3], pm[j3]);
      alpha[j3] = __expf(mrow[j3] - mn);   // exp(-inf)=0 on first tile
      mrow[j3] = mn;
    }
    float rs[4] = {0.f, 0.f, 0.f, 0.f};
#pragma unroll
    for (int n = 0; n < 4; ++n)
#pragma unroll
      for (int j3 = 0; j3 < 4; ++j3) {
        float p = __expf(sv[n][j3] - mrow[j3]);
        sv[n][j3] = p;
        rs[j3] += p;
      }
#pragma unroll
    for (int m = 1; m < 16; m <<= 1)
#pragma unroll
      for (int j3 = 0; j3 < 4; ++j3) rs[j3] += __shfl_xor(rs[j3], m, 64);
#pragma unroll
    for (int j3 = 0; j3 < 4; ++j3) lrow[j3] = lrow[j3] * alpha[j3] + rs[j3];
#pragma unroll
    for (int n = 0; n < 8; ++n)
#pragma unroll
      for (int j3 = 0; j3 < 4; ++j3) acc[n][j3] *= alpha[j3];

    // P -> per-wave LDS (bf16), then read as PV A-fragments
    unsigned short* pl = &Ps[w][0];
#pragma unroll
    for (int n = 0; n < 4; ++n)
#pragma unroll
      for (int j3 = 0; j3 < 4; ++j3)
        pl[(fq * 4 + j3) * 72 + n * 16 + fr] = f2bf(sv[n][j3]);
    asm volatile("s_waitcnt lgkmcnt(0)" ::: "memory");
#pragma unroll
    for (int ks = 0; ks < 2; ++ks) {
      bf16x8 pa = *(const bf16x8*)&pl[fr * 72 + ks * 32 + fq * 8];
#pragma unroll
      for (int n = 0; n < 8; ++n) {
        bf16x8 bv = *(const bf16x8*)&Vts[(n * 16 + fr) * 64 + ks * 32 + fq * 8];
        acc[n] = __builtin_amdgcn_mfma_f32_16x16x32_bf16(pa, bv, acc[n], 0, 0, 0);
      }
    }
  }

  // epilogue: y[t][h*128+d] bf16
#pragma unroll
  for (int j3 = 0; j3 < 4; ++j3) {
    float inv = 1.0f / lrow[j3];
    int t = qb * 64 + w * 16 + fq * 4 + j3;
#pragma unroll
    for (int n = 0; n < 8; ++n)
      yb[(long)t * HS + h * 128 + n * 16 + fr] = f2bf(acc[n][j3] * inv);
  }
}

// ---------------- launch ----------------
extern "C" void kernel_launch(void* const* d_in, const int* in_sizes, int n_in,
                              void* d_out, int out_size, void* d_ws, size_t ws_size,
                              hipStream_t stream) {
  const float* x    = (const float*)d_in[0];
  const float* Wqkv = (const float*)d_in[1];
  const float* Wo_w = (const float*)d_in[2];
  const float* Wo_b = (const float*)d_in[3];
  float* out = (float*)d_out;
  char* ws = (char*)d_ws;

  unsigned short* xbf  = (unsigned short*)(ws + 0L);          //  8.0 MB
  unsigned short* wqbf = (unsigned short*)(ws + 8388608L);    // 24.0 MB
  unsigned short* wobf = (unsigned short*)(ws + 33554432L);   //  8.0 MB
  float*          qkv  = (float*)         (ws + 41943040L);   // 48.0 MB
  unsigned short* qb   = (unsigned short*)(ws + 92274688L);   //  8.0 MB
  unsigned short* kb   = (unsigned short*)(ws + 100663296L);  //  8.0 MB
  unsigned short* vt   = (unsigned short*)(ws + 109051904L);  //  8.0 MB
  unsigned short* yb   = (unsigned short*)(ws + 117440512L);  //  8.0 MB
  float*          cosd = (float*)         (ws + 125829120L);  //  0.5 MB
  float*          sind = (float*)         (ws + 126353408L);  //  0.5 MB

  cast_bf16_kernel<<<dim3(4194304 / 8 / 256), 256, 0, stream>>>(x, xbf, 4194304);
  cast_bf16_kernel<<<dim3(12582912 / 8 / 256), 256, 0, stream>>>(Wqkv, wqbf, 12582912);
  cast_bf16_kernel<<<dim3(4194304 / 8 / 256), 256, 0, stream>>>(Wo_w, wobf, 4194304);
  rope_table_kernel<<<dim3(512), 256, 0, stream>>>(cosd, sind);

  gemm_bt<0><<<dim3(QKVN / 128, T_SEQ / 128), 256, 0, stream>>>(xbf, wqbf, qkv, nullptr,
                                                                T_SEQ, QKVN, HS);
  normrope_qk<<<dim3(T_SEQ, 2 * NH), 128, 0, stream>>>(qkv, cosd, sind, qb, kb);
  v_transpose<<<dim3(T_SEQ / 64, NH), 256, 0, stream>>>(qkv, vt);
  attn_kernel<<<dim3(512), 256, 0, stream>>>(qb, kb, vt, yb);
  gemm_bt<1><<<dim3(HS / 128, T_SEQ / 128), 256, 0, stream>>>(yb, wobf, out, Wo_b,
                                                              T_SEQ, HS, HS);
}

// Round 5
// 322.846 us; speedup vs baseline: 1.2305x; 1.0842x over previous
//
#include <hip/hip_runtime.h>
#include <hip/hip_bf16.h>
#include <stdint.h>

#define T_SEQ 2048
#define HS    2048
#define NH    16
#define DH    128
#define QKVN  (3*HS)

typedef __attribute__((ext_vector_type(8))) short          bf16x8;
typedef __attribute__((ext_vector_type(4))) float          f32x4;
typedef __attribute__((ext_vector_type(4))) unsigned short us4;
typedef __attribute__((ext_vector_type(8))) unsigned short us8;

// round-to-nearest-even f32 -> bf16 bits
__device__ __forceinline__ unsigned short f2bf(float x) {
  unsigned int u = __float_as_uint(x);
  return (unsigned short)((u + 0x7fffu + ((u >> 16) & 1u)) >> 16);
}

// async global->LDS, 16B per lane; lds base must be wave-uniform (lane i lands at base + i*16B)
__device__ __forceinline__ void gl_lds16(const void* g, void* l) {
  __builtin_amdgcn_global_load_lds((__attribute__((address_space(1))) void*)g,
                                   (__attribute__((address_space(3))) void*)l, 16, 0, 0);
}

// ---------------- elementwise cast f32 -> bf16 (vectorized 8/thread) ----------------
__global__ __launch_bounds__(256) void cast_bf16_kernel(const float* __restrict__ in,
                                                        unsigned short* __restrict__ out, int n) {
  int i = (blockIdx.x * 256 + threadIdx.x) * 8;
  if (i >= n) return;
  f32x4 a = *(const f32x4*)(in + i);
  f32x4 b = *(const f32x4*)(in + i + 4);
  us8 r;
#pragma unroll
  for (int j = 0; j < 4; ++j) { r[j] = f2bf(a[j]); r[j + 4] = f2bf(b[j]); }
  *(us8*)(out + i) = r;
}

// ---------------- RoPE cos/sin table [T][64] ----------------
__global__ __launch_bounds__(256) void rope_table_kernel(float* __restrict__ cosd,
                                                         float* __restrict__ sind) {
  int i = blockIdx.x * 256 + threadIdx.x;   // over T*64
  if (i >= T_SEQ * 64) return;
  int t = i >> 6, f = i & 63;
  float inv = expf(-9.210340371976184f * (float)f * (1.0f / 64.0f));
  float ang = (float)t * inv;
  float s, c;
  sincosf(ang, &s, &c);
  cosd[i] = c; sind[i] = s;
}

// ---------------- GEMM C[M][N] = A[M][K](bf16) * Bt[N][K](bf16)^T (+bias) ----------------
// 128x128 tile, BK=64, 256 threads (4 waves, each 64x64 out), mfma_f32_16x16x32_bf16
template <int BIAS>
__global__ __launch_bounds__(256, 2)
void gemm_bt(const unsigned short* __restrict__ A, const unsigned short* __restrict__ Bt,
             float* __restrict__ C, const float* __restrict__ bias, int M, int N, int K) {
  __shared__ unsigned short As[128 * 64];
  __shared__ unsigned short Bs[128 * 64];
  const int tid  = threadIdx.x;
  const int lane = tid & 63;
  const int w    = tid >> 6;
  const int fr   = lane & 15;   // fragment row/col
  const int fq   = lane >> 4;   // k-group
  const int bm   = blockIdx.y * 128;
  const int bn   = blockIdx.x * 128;
  const int wr   = (w >> 1) * 64;
  const int wc   = (w & 1) * 64;

  f32x4 acc[4][4];
#pragma unroll
  for (int m = 0; m < 4; ++m)
#pragma unroll
    for (int n = 0; n < 4; ++n) { acc[m][n][0]=0.f; acc[m][n][1]=0.f; acc[m][n][2]=0.f; acc[m][n][3]=0.f; }

  const int srow = lane >> 3;        // 8 rows per load-instr (128B rows)
  const int scol = (lane & 7) * 8;   // element offset within row
  const unsigned short* Ag = A + (long)bm * K;
  const unsigned short* Bg = Bt + (long)bn * K;

  const int nk = K >> 6;
  for (int kt = 0; kt < nk; ++kt) {
    const int k0 = kt << 6;
    __syncthreads();               // previous compute done, LDS free
#pragma unroll
    for (int i = 0; i < 4; ++i) {
      int r = i * 32 + w * 8;      // wave-uniform chunk base row
      gl_lds16(Ag + (long)(r + srow) * K + k0 + scol, &As[r * 64]);
      gl_lds16(Bg + (long)(r + srow) * K + k0 + scol, &Bs[r * 64]);
    }
    __syncthreads();               // drains vmcnt(0): tiles resident
#pragma unroll
    for (int ks = 0; ks < 2; ++ks) {
      bf16x8 af[4], bfr[4];
#pragma unroll
      for (int m = 0; m < 4; ++m) af[m]  = *(const bf16x8*)&As[(wr + m * 16 + fr) * 64 + ks * 32 + fq * 8];
#pragma unroll
      for (int n = 0; n < 4; ++n) bfr[n] = *(const bf16x8*)&Bs[(wc + n * 16 + fr) * 64 + ks * 32 + fq * 8];
#pragma unroll
      for (int m = 0; m < 4; ++m)
#pragma unroll
        for (int n = 0; n < 4; ++n)
          acc[m][n] = __builtin_amdgcn_mfma_f32_16x16x32_bf16(af[m], bfr[n], acc[m][n], 0, 0, 0);
    }
  }
  // epilogue: C/D layout col=lane&15, row=(lane>>4)*4+reg
#pragma unroll
  for (int m = 0; m < 4; ++m) {
    int row0 = bm + wr + m * 16 + fq * 4;
#pragma unroll
    for (int n = 0; n < 4; ++n) {
      int col = bn + wc + n * 16 + fr;
      float bv = BIAS ? bias[col] : 0.0f;
#pragma unroll
      for (int j = 0; j < 4; ++j)
        C[(long)(row0 + j) * N + col] = acc[m][n][j] + bv;
    }
  }
}

// ---------------- fused RMSNorm + RoPE for q,k; writes bf16 [h][t][d] ----------------
__global__ __launch_bounds__(128)
void normrope_qk(const float* __restrict__ qkv, const float* __restrict__ cosd,
                 const float* __restrict__ sind, unsigned short* __restrict__ qb,
                 unsigned short* __restrict__ kb) {
  const int t = blockIdx.x;
  const int y = blockIdx.y;          // 0..31 : q heads then k heads
  const int kind = y >> 4;
  const int h = y & 15;
  const int d = threadIdx.x;         // 0..127
  float x = qkv[(long)t * QKVN + y * 128 + d];
  float ss = x * x;
#pragma unroll
  for (int m = 1; m < 64; m <<= 1) ss += __shfl_xor(ss, m, 64);
  __shared__ float red[2];
  __shared__ float xn[128];
  if ((d & 63) == 0) red[d >> 6] = ss;
  __syncthreads();
  ss = red[0] + red[1];
  float r = rsqrtf(ss * (1.0f / 128.0f) + 1.1920928955078125e-07f);
  float v = x * r;
  xn[d] = v;
  __syncthreads();
  float o;
  if (d < 64) {
    float c = cosd[t * 64 + d], s = sind[t * 64 + d];
    o = v * c + xn[d + 64] * s;
  } else {
    float c = cosd[t * 64 + d - 64], s = sind[t * 64 + d - 64];
    o = -xn[d - 64] * s + v * c;
  }
  unsigned short* dst = kind ? kb : qb;
  dst[((long)h * T_SEQ + t) * 128 + d] = f2bf(o);
}

// ---------------- V: cast + transpose to [h][d][t] bf16 ----------------
__global__ __launch_bounds__(256)
void v_transpose(const float* __restrict__ qkv, unsigned short* __restrict__ vt) {
  const int tb = blockIdx.x;   // 64-row t tile
  const int h  = blockIdx.y;
  __shared__ unsigned short vl[128][72];   // pad: row stride 144B (16B aligned)
  const int tid = threadIdx.x;
#pragma unroll
  for (int p = 0; p < 32; ++p) {
    int rr = p * 2 + (tid >> 7);
    int d  = tid & 127;
    float x = qkv[(long)(tb * 64 + rr) * QKVN + 2 * HS + h * 128 + d];
    vl[d][rr] = f2bf(x);
  }
  __syncthreads();
#pragma unroll
  for (int p = 0; p < 8; ++p) {
    int idx = (p * 256 + tid) * 4;   // elem in [128][64]
    int d = idx >> 6;
    int i = idx & 63;
    us4 val = *(const us4*)&vl[d][i];
    *(us4*)&vt[((long)h * DH + d) * T_SEQ + tb * 64 + i] = val;
  }
}

// ---------------- causal flash attention ----------------
// 1D grid of 512 blocks; balanced (qb,h) remap: co-resident blocks i, i+256 get
// complementary causal work. 2-phase pipeline: stage tile kt+1 into alt LDS buf
// while computing kt (one vmcnt-drain barrier per tile). K/V LDS XOR-swizzled
// (granule ^= row&7) via pre-swizzled GLOBAL source (gl_lds dest stays linear)
// + matching XOR on ds_read addresses.
__global__ __launch_bounds__(256, 2)
void attn_kernel(const unsigned short* __restrict__ qg, const unsigned short* __restrict__ kg,
                 const unsigned short* __restrict__ vtg, unsigned short* __restrict__ yb) {
  const int bi = blockIdx.x;
  const int j  = (bi < 256) ? bi : bi - 256;
  const int h  = j & 15;
  const int q0 = j >> 4;                       // 0..15
  const int qb = (bi < 256) ? (31 - q0) : q0;  // first half long, second half short

  __shared__ unsigned short Ks[2][64 * 128];
  __shared__ unsigned short Vts[2][128 * 64];
  __shared__ unsigned short Ps[4][16 * 72];   // per-wave P tile, padded rows (144B)

  const int tid = threadIdx.x, lane = tid & 63, w = tid >> 6;
  const int fr = lane & 15, fq = lane >> 4;

  const unsigned short* qh = qg  + (long)h * T_SEQ * 128;
  const unsigned short* kh = kg  + (long)h * T_SEQ * 128;
  const unsigned short* vh = vtg + (long)h * 128 * T_SEQ;

  // K staging geometry: instr i covers rows 4c..4c+3 (c=w*4+i); lane: row=4c+(lane>>4),
  // LDS granule pos p=lane&15; source granule g = p ^ (row&7)  (swizzle inverse)
  const int krow_off = lane >> 4;          // 0..3
  // V staging: instr i covers rows r0..r0+7 (r0=(w*4+i)*8); lane: row=r0+(lane>>3),
  // pos=lane&7; source granule g=(lane&7)^(lane>>3)  (row&7 == lane>>3)
  const int vrow_off = lane >> 3;          // 0..7
  const int vg       = (lane & 7) ^ vrow_off;

  // prologue: stage tile 0 -> buf 0
  {
#pragma unroll
    for (int i = 0; i < 4; ++i) {
      int c = w * 4 + i;
      int r = 4 * c + krow_off;
      int g = (lane & 15) ^ (r & 7);
      gl_lds16(kh + r * 128 + g * 8, &Ks[0][c * 512]);
    }
#pragma unroll
    for (int i = 0; i < 4; ++i) {
      int r0 = (w * 4 + i) * 8;
      gl_lds16(vh + (long)(r0 + vrow_off) * T_SEQ + vg * 8, &Vts[0][r0 * 64]);
    }
  }

  // Q fragments straight from global (read once, no LDS round-trip)
  bf16x8 aq[4];
  {
    const unsigned short* qrow = qh + (long)(qb * 64 + w * 16 + fr) * 128;
#pragma unroll
    for (int ks = 0; ks < 4; ++ks)
      aq[ks] = *(const bf16x8*)(qrow + ks * 32 + fq * 8);
  }

  f32x4 acc[8];
#pragma unroll
  for (int n = 0; n < 8; ++n) { acc[n][0]=0.f; acc[n][1]=0.f; acc[n][2]=0.f; acc[n][3]=0.f; }
  float mrow[4], lrow[4];
#pragma unroll
  for (int j2 = 0; j2 < 4; ++j2) { mrow[j2] = -__builtin_huge_valf(); lrow[j2] = 0.f; }

  const float scale = 0.08838834764831845f;   // 1/sqrt(128)

  __syncthreads();   // vmcnt(0)+barrier: tile 0 resident

  for (int kt = 0; kt <= qb; ++kt) {
    const int cur = kt & 1;

    // issue next tile's staging into alt buffer (lands during this tile's compute)
    if (kt < qb) {
      const int nb = cur ^ 1;
      const unsigned short* ksrc = kh + (kt + 1) * (64 * 128);
      const unsigned short* vsrc = vh + (kt + 1) * 64;
#pragma unroll
      for (int i = 0; i < 4; ++i) {
        int c = w * 4 + i;
        int r = 4 * c + krow_off;
        int g = (lane & 15) ^ (r & 7);
        gl_lds16(ksrc + r * 128 + g * 8, &Ks[nb][c * 512]);
      }
#pragma unroll
      for (int i = 0; i < 4; ++i) {
        int r0 = (w * 4 + i) * 8;
        gl_lds16(vsrc + (long)(r0 + vrow_off) * T_SEQ + vg * 8, &Vts[nb][r0 * 64]);
      }
    }

    // S = Q K^T (16 x 64 per wave); K rows read with swizzled granule
    f32x4 sv[4];
#pragma unroll
    for (int n = 0; n < 4; ++n) { sv[n][0]=0.f; sv[n][1]=0.f; sv[n][2]=0.f; sv[n][3]=0.f; }
    __builtin_amdgcn_s_setprio(1);
#pragma unroll
    for (int ks = 0; ks < 4; ++ks)
#pragma unroll
      for (int n = 0; n < 4; ++n) {
        int R = n * 16 + fr;
        bf16x8 bk = *(const bf16x8*)&Ks[cur][R * 128 + (((ks * 4 + fq) ^ (fr & 7)) << 3)];
        sv[n] = __builtin_amdgcn_mfma_f32_16x16x32_bf16(aq[ks], bk, sv[n], 0, 0, 0);
      }
    __builtin_amdgcn_s_setprio(0);

    // scale + causal mask (only diagonal tile can mask)
#pragma unroll
    for (int n = 0; n < 4; ++n)
#pragma unroll
      for (int j3 = 0; j3 < 4; ++j3) {
        float s = sv[n][j3] * scale;
        if (kt == qb && (n * 16 + fr) > (w * 16 + fq * 4 + j3)) s = -__builtin_huge_valf();
        sv[n][j3] = s;
      }

    // row max over 64 cols: local over n, then 16-lane butterfly
    float pm[4];
#pragma unroll
    for (int j3 = 0; j3 < 4; ++j3)
      pm[j3] = fmaxf(fmaxf(sv[0][j3], sv[1][j3]), fmaxf(sv[2][j3], sv[3][j3]));
#pragma unroll
    for (int m = 1; m < 16; m <<= 1)
#pragma unroll
      for (int j3 = 0; j3 < 4; ++j3) pm[j3] = fmaxf(pm[j3], __shfl_xor(pm[j3], m, 64));

    float alpha[4];
#pragma unroll
    for (int j3 = 0; j3 < 4; ++j3) {
      float mn = fmaxf(mrow[j3], pm[j3]);
      alpha[j3] = __expf(mrow[j3] - mn);   // exp(-inf)=0 on first tile
      mrow[j3] = mn;
    }
    float rs[4] = {0.f, 0.f, 0.f, 0.f};
#pragma unroll
    for (int n = 0; n < 4; ++n)
#pragma unroll
      for (int j3 = 0; j3 < 4; ++j3) {
        float p = __expf(sv[n][j3] - mrow[j3]);
        sv[n][j3] = p;
        rs[j3] += p;
      }
#pragma unroll
    for (int m = 1; m < 16; m <<= 1)
#pragma unroll
      for (int j3 = 0; j3 < 4; ++j3) rs[j3] += __shfl_xor(rs[j3], m, 64);
#pragma unroll
    for (int j3 = 0; j3 < 4; ++j3) lrow[j3] = lrow[j3] * alpha[j3] + rs[j3];
#pragma unroll
    for (int n = 0; n < 8; ++n)
#pragma unroll
      for (int j3 = 0; j3 < 4; ++j3) acc[n][j3] *= alpha[j3];

    // P -> per-wave LDS (bf16), then read as PV A-fragments
    unsigned short* pl = &Ps[w][0];
#pragma unroll
    for (int n = 0; n < 4; ++n)
#pragma unroll
      for (int j3 = 0; j3 < 4; ++j3)
        pl[(fq * 4 + j3) * 72 + n * 16 + fr] = f2bf(sv[n][j3]);
    asm volatile("s_waitcnt lgkmcnt(0)" ::: "memory");
    __builtin_amdgcn_s_setprio(1);
#pragma unroll
    for (int ks = 0; ks < 2; ++ks) {
      bf16x8 pa = *(const bf16x8*)&pl[fr * 72 + ks * 32 + fq * 8];
#pragma unroll
      for (int n = 0; n < 8; ++n) {
        int R = n * 16 + fr;
        bf16x8 bv = *(const bf16x8*)&Vts[cur][R * 64 + (((ks * 4 + fq) ^ (fr & 7)) << 3)];
        acc[n] = __builtin_amdgcn_mfma_f32_16x16x32_bf16(pa, bv, acc[n], 0, 0, 0);
      }
    }
    __builtin_amdgcn_s_setprio(0);

    __syncthreads();   // vmcnt(0)+lgkmcnt(0)+barrier: next tile resident, this buf reusable
  }

  // epilogue: y[t][h*128+d] bf16
#pragma unroll
  for (int j3 = 0; j3 < 4; ++j3) {
    float inv = 1.0f / lrow[j3];
    int t = qb * 64 + w * 16 + fq * 4 + j3;
#pragma unroll
    for (int n = 0; n < 8; ++n)
      yb[(long)t * HS + h * 128 + n * 16 + fr] = f2bf(acc[n][j3] * inv);
  }
}

// ---------------- launch ----------------
extern "C" void kernel_launch(void* const* d_in, const int* in_sizes, int n_in,
                              void* d_out, int out_size, void* d_ws, size_t ws_size,
                              hipStream_t stream) {
  const float* x    = (const float*)d_in[0];
  const float* Wqkv = (const float*)d_in[1];
  const float* Wo_w = (const float*)d_in[2];
  const float* Wo_b = (const float*)d_in[3];
  float* out = (float*)d_out;
  char* ws = (char*)d_ws;

  unsigned short* xbf  = (unsigned short*)(ws + 0L);          //  8.0 MB
  unsigned short* wqbf = (unsigned short*)(ws + 8388608L);    // 24.0 MB
  unsigned short* wobf = (unsigned short*)(ws + 33554432L);   //  8.0 MB
  float*          qkv  = (float*)         (ws + 41943040L);   // 48.0 MB
  unsigned short* qb   = (unsigned short*)(ws + 92274688L);   //  8.0 MB
  unsigned short* kb   = (unsigned short*)(ws + 100663296L);  //  8.0 MB
  unsigned short* vt   = (unsigned short*)(ws + 109051904L);  //  8.0 MB
  unsigned short* yb   = (unsigned short*)(ws + 117440512L);  //  8.0 MB
  float*          cosd = (float*)         (ws + 125829120L);  //  0.5 MB
  float*          sind = (float*)         (ws + 126353408L);  //  0.5 MB

  cast_bf16_kernel<<<dim3(4194304 / 8 / 256), 256, 0, stream>>>(x, xbf, 4194304);
  cast_bf16_kernel<<<dim3(12582912 / 8 / 256), 256, 0, stream>>>(Wqkv, wqbf, 12582912);
  cast_bf16_kernel<<<dim3(4194304 / 8 / 256), 256, 0, stream>>>(Wo_w, wobf, 4194304);
  rope_table_kernel<<<dim3(512), 256, 0, stream>>>(cosd, sind);

  gemm_bt<0><<<dim3(QKVN / 128, T_SEQ / 128), 256, 0, stream>>>(xbf, wqbf, qkv, nullptr,
                                                                T_SEQ, QKVN, HS);
  normrope_qk<<<dim3(T_SEQ, 2 * NH), 128, 0, stream>>>(qkv, cosd, sind, qb, kb);
  v_transpose<<<dim3(T_SEQ / 64, NH), 256, 0, stream>>>(qkv, vt);
  attn_kernel<<<dim3(512), 256, 0, stream>>>(qb, kb, vt, yb);
  gemm_bt<1><<<dim3(HS / 128, T_SEQ / 128), 256, 0, stream>>>(yb, wobf, out, Wo_b,
                                                              T_SEQ, HS, HS);
}

// Round 7
// 297.366 us; speedup vs baseline: 1.3360x; 1.0857x over previous
//
#include <hip/hip_runtime.h>
#include <hip/hip_bf16.h>
#include <stdint.h>

#define T_SEQ 2048
#define HS    2048
#define NH    16
#define DH    128
#define QKVN  (3*HS)

typedef __attribute__((ext_vector_type(8))) short          bf16x8;
typedef __attribute__((ext_vector_type(4))) float          f32x4;
typedef __attribute__((ext_vector_type(4))) unsigned short us4;
typedef __attribute__((ext_vector_type(8))) unsigned short us8;

// round-to-nearest-even f32 -> bf16 bits
__device__ __forceinline__ unsigned short f2bf(float x) {
  unsigned int u = __float_as_uint(x);
  return (unsigned short)((u + 0x7fffu + ((u >> 16) & 1u)) >> 16);
}

// async global->LDS, 16B per lane; lds base must be wave-uniform (lane i lands at base + i*16B)
__device__ __forceinline__ void gl_lds16(const void* g, void* l) {
  __builtin_amdgcn_global_load_lds((__attribute__((address_space(1))) void*)g,
                                   (__attribute__((address_space(3))) void*)l, 16, 0, 0);
}

// ---------------- elementwise cast f32 -> bf16 (vectorized 8/thread) ----------------
__global__ __launch_bounds__(256) void cast_bf16_kernel(const float* __restrict__ in,
                                                        unsigned short* __restrict__ out, int n) {
  int i = (blockIdx.x * 256 + threadIdx.x) * 8;
  if (i >= n) return;
  f32x4 a = *(const f32x4*)(in + i);
  f32x4 b = *(const f32x4*)(in + i + 4);
  us8 r;
#pragma unroll
  for (int j = 0; j < 4; ++j) { r[j] = f2bf(a[j]); r[j + 4] = f2bf(b[j]); }
  *(us8*)(out + i) = r;
}

// ---------------- RoPE cos/sin table [T][64] ----------------
__global__ __launch_bounds__(256) void rope_table_kernel(float* __restrict__ cosd,
                                                         float* __restrict__ sind) {
  int i = blockIdx.x * 256 + threadIdx.x;   // over T*64
  if (i >= T_SEQ * 64) return;
  int t = i >> 6, f = i & 63;
  float inv = expf(-9.210340371976184f * (float)f * (1.0f / 64.0f));
  float ang = (float)t * inv;
  float s, c;
  sincosf(ang, &s, &c);
  cosd[i] = c; sind[i] = s;
}

// ---------------- GEMM C[M][N] = A[M][K](bf16) * Bt[N][K](bf16)^T (+bias) ----------------
// 128xBN tile, BK=64, 256 threads (4 waves). LDS granule XOR-swizzle (g ^= row&7)
// applied via pre-swizzled global source (gl_lds dest linear) + same XOR on reads.
// launch_bounds(256,4): 4 blocks/CU capacity -> cross-block overlap hides barrier drain.
template <int BIAS, int BN>
__global__ __launch_bounds__(256, 4)
void gemm_bt(const unsigned short* __restrict__ A, const unsigned short* __restrict__ Bt,
             float* __restrict__ C, const float* __restrict__ bias, int M, int N, int K) {
  constexpr int FN = BN / 32;          // n-fragments per wave (128->4, 64->2)
  __shared__ unsigned short As[128 * 64];
  __shared__ unsigned short Bs[BN * 64];
  const int tid  = threadIdx.x;
  const int lane = tid & 63;
  const int w    = tid >> 6;
  const int fr   = lane & 15;   // fragment row/col
  const int fq   = lane >> 4;   // k-group
  const int bm   = blockIdx.y * 128;
  const int bn   = blockIdx.x * BN;
  const int wr   = (w >> 1) * 64;
  const int wc   = (w & 1) * (BN / 2);

  f32x4 acc[4][FN];
#pragma unroll
  for (int m = 0; m < 4; ++m)
#pragma unroll
    for (int n = 0; n < FN; ++n) { acc[m][n][0]=0.f; acc[m][n][1]=0.f; acc[m][n][2]=0.f; acc[m][n][3]=0.f; }

  // staging: instr covers 8 rows; lane -> row = base + (lane>>3), granule pos = lane&7.
  // swizzled source granule g = (lane&7) ^ (row&7) = (lane&7) ^ (lane>>3)  (base % 8 == 0)
  const int srow = lane >> 3;
  const int sg   = (lane & 7) ^ srow;
  const unsigned short* Ag = A + (long)bm * K;
  const unsigned short* Bg = Bt + (long)bn * K;

  const int nk = K >> 6;
  for (int kt = 0; kt < nk; ++kt) {
    const int k0 = kt << 6;
    __syncthreads();               // previous compute done, LDS free
#pragma unroll
    for (int i = 0; i < 4; ++i) {
      int r = i * 32 + w * 8;      // wave-uniform chunk base row
      gl_lds16(Ag + (long)(r + srow) * K + k0 + sg * 8, &As[r * 64]);
    }
#pragma unroll
    for (int i = 0; i < BN / 32; ++i) {
      int r = i * 32 + w * 8;
      gl_lds16(Bg + (long)(r + srow) * K + k0 + sg * 8, &Bs[r * 64]);
    }
    __syncthreads();               // drains vmcnt(0): tiles resident
    __builtin_amdgcn_s_setprio(1);
#pragma unroll
    for (int ks = 0; ks < 2; ++ks) {
      bf16x8 af[4], bfr[FN];
#pragma unroll
      for (int m = 0; m < 4; ++m)
        af[m]  = *(const bf16x8*)&As[(wr + m * 16 + fr) * 64 + (((ks * 4 + fq) ^ (fr & 7)) << 3)];
#pragma unroll
      for (int n = 0; n < FN; ++n)
        bfr[n] = *(const bf16x8*)&Bs[(wc + n * 16 + fr) * 64 + (((ks * 4 + fq) ^ (fr & 7)) << 3)];
#pragma unroll
      for (int m = 0; m < 4; ++m)
#pragma unroll
        for (int n = 0; n < FN; ++n)
          acc[m][n] = __builtin_amdgcn_mfma_f32_16x16x32_bf16(af[m], bfr[n], acc[m][n], 0, 0, 0);
    }
    __builtin_amdgcn_s_setprio(0);
  }
  // epilogue: C/D layout col=lane&15, row=(lane>>4)*4+reg
#pragma unroll
  for (int m = 0; m < 4; ++m) {
    int row0 = bm + wr + m * 16 + fq * 4;
#pragma unroll
    for (int n = 0; n < FN; ++n) {
      int col = bn + wc + n * 16 + fr;
      float bv = BIAS ? bias[col] : 0.0f;
#pragma unroll
      for (int j = 0; j < 4; ++j)
        C[(long)(row0 + j) * N + col] = acc[m][n][j] + bv;
    }
  }
}

// ---------------- fused RMSNorm + RoPE for q,k; writes bf16 [h][t][d] ----------------
// wave-per-row: 64 lanes x float2, shfl-only reduction, no LDS/__syncthreads.
// 1024 blocks x 256 thr = 4096 waves; 65536 rows grid-strided (16 rows/wave).
__global__ __launch_bounds__(256)
void normrope_qk(const float* __restrict__ qkv, const float* __restrict__ cosd,
                 const float* __restrict__ sind, unsigned short* __restrict__ qb,
                 unsigned short* __restrict__ kb) {
  const int wgl  = (blockIdx.x * 256 + threadIdx.x) >> 6;  // global wave id 0..4095
  const int lane = threadIdx.x & 63;
  for (int rr = wgl; rr < T_SEQ * 32; rr += 4096) {
    const int t = rr >> 5;
    const int y = rr & 31;               // 0..15 q heads, 16..31 k heads
    const float2 v = *(const float2*)(qkv + (long)t * QKVN + y * 128 + lane * 2);
    float ss = v.x * v.x + v.y * v.y;
#pragma unroll
    for (int m = 1; m < 64; m <<= 1) ss += __shfl_xor(ss, m, 64);
    const float r = rsqrtf(ss * (1.0f / 128.0f) + 1.1920928955078125e-07f);
    const float a = v.x * r, b = v.y * r;
    const float pa = __shfl_xor(a, 32, 64), pb = __shfl_xor(b, 32, 64);
    const float2 c2 = *(const float2*)(cosd + t * 64 + (lane & 31) * 2);
    const float2 s2 = *(const float2*)(sind + t * 64 + (lane & 31) * 2);
    float o0, o1;
    if (lane < 32) { o0 =  a * c2.x + pa * s2.x;  o1 =  b * c2.y + pb * s2.y; }
    else           { o0 = -pa * s2.x + a * c2.x;  o1 = -pb * s2.y + b * c2.y; }
    unsigned short* dst = (y >> 4) ? kb : qb;
    const unsigned int packed = (unsigned int)f2bf(o0) | ((unsigned int)f2bf(o1) << 16);
    *(unsigned int*)(dst + ((long)(y & 15) * T_SEQ + t) * 128 + lane * 2) = packed;
  }
}

// ---------------- V: cast + transpose to [h][d][t] bf16 ----------------
__global__ __launch_bounds__(256)
void v_transpose(const float* __restrict__ qkv, unsigned short* __restrict__ vt) {
  const int tb = blockIdx.x;   // 64-row t tile
  const int h  = blockIdx.y;
  __shared__ unsigned short vl[128][72];   // pad: row stride 144B (16B aligned)
  const int tid = threadIdx.x;
#pragma unroll
  for (int p = 0; p < 32; ++p) {
    int rr = p * 2 + (tid >> 7);
    int d  = tid & 127;
    float x = qkv[(long)(tb * 64 + rr) * QKVN + 2 * HS + h * 128 + d];
    vl[d][rr] = f2bf(x);
  }
  __syncthreads();
#pragma unroll
  for (int p = 0; p < 8; ++p) {
    int idx = (p * 256 + tid) * 4;   // elem in [128][64]
    int d = idx >> 6;
    int i = idx & 63;
    us4 val = *(const us4*)&vl[d][i];
    *(us4*)&vt[((long)h * DH + d) * T_SEQ + tb * 64 + i] = val;
  }
}

// ---------------- causal flash attention ----------------
// 1D grid of 512 blocks; balanced (qb,h) remap: co-resident blocks i, i+256 get
// complementary causal work. 2-phase pipeline: stage tile kt+1 into alt LDS buf
// while computing kt (one vmcnt-drain barrier per tile). K/V LDS XOR-swizzled
// (granule ^= row&7) via pre-swizzled GLOBAL source (gl_lds dest stays linear)
// + matching XOR on ds_read addresses.
__global__ __launch_bounds__(256, 2)
void attn_kernel(const unsigned short* __restrict__ qg, const unsigned short* __restrict__ kg,
                 const unsigned short* __restrict__ vtg, unsigned short* __restrict__ yb) {
  const int bi = blockIdx.x;
  const int j  = (bi < 256) ? bi : bi - 256;
  const int h  = j & 15;
  const int q0 = j >> 4;                       // 0..15
  const int qb = (bi < 256) ? (31 - q0) : q0;  // first half long, second half short

  __shared__ unsigned short Ks[2][64 * 128];
  __shared__ unsigned short Vts[2][128 * 64];
  __shared__ unsigned short Ps[4][16 * 72];   // per-wave P tile, padded rows (144B)

  const int tid = threadIdx.x, lane = tid & 63, w = tid >> 6;
  const int fr = lane & 15, fq = lane >> 4;

  const unsigned short* qh = qg  + (long)h * T_SEQ * 128;
  const unsigned short* kh = kg  + (long)h * T_SEQ * 128;
  const unsigned short* vh = vtg + (long)h * 128 * T_SEQ;

  // K staging geometry: instr i covers rows 4c..4c+3 (c=w*4+i); lane: row=4c+(lane>>4),
  // LDS granule pos p=lane&15; source granule g = p ^ (row&7)  (swizzle inverse)
  const int krow_off = lane >> 4;          // 0..3
  // V staging: instr i covers rows r0..r0+7 (r0=(w*4+i)*8); lane: row=r0+(lane>>3),
  // pos=lane&7; source granule g=(lane&7)^(lane>>3)  (row&7 == lane>>3)
  const int vrow_off = lane >> 3;          // 0..7
  const int vg       = (lane & 7) ^ vrow_off;

  // prologue: stage tile 0 -> buf 0
  {
#pragma unroll
    for (int i = 0; i < 4; ++i) {
      int c = w * 4 + i;
      int r = 4 * c + krow_off;
      int g = (lane & 15) ^ (r & 7);
      gl_lds16(kh + r * 128 + g * 8, &Ks[0][c * 512]);
    }
#pragma unroll
    for (int i = 0; i < 4; ++i) {
      int r0 = (w * 4 + i) * 8;
      gl_lds16(vh + (long)(r0 + vrow_off) * T_SEQ + vg * 8, &Vts[0][r0 * 64]);
    }
  }

  // Q fragments straight from global (read once, no LDS round-trip)
  bf16x8 aq[4];
  {
    const unsigned short* qrow = qh + (long)(qb * 64 + w * 16 + fr) * 128;
#pragma unroll
    for (int ks = 0; ks < 4; ++ks)
      aq[ks] = *(const bf16x8*)(qrow + ks * 32 + fq * 8);
  }

  f32x4 acc[8];
#pragma unroll
  for (int n = 0; n < 8; ++n) { acc[n][0]=0.f; acc[n][1]=0.f; acc[n][2]=0.f; acc[n][3]=0.f; }
  float mrow[4], lrow[4];
#pragma unroll
  for (int j2 = 0; j2 < 4; ++j2) { mrow[j2] = -__builtin_huge_valf(); lrow[j2] = 0.f; }

  const float scale = 0.08838834764831845f;   // 1/sqrt(128)

  __syncthreads();   // vmcnt(0)+barrier: tile 0 resident

  for (int kt = 0; kt <= qb; ++kt) {
    const int cur = kt & 1;

    // issue next tile's staging into alt buffer (lands during this tile's compute)
    if (kt < qb) {
      const int nb = cur ^ 1;
      const unsigned short* ksrc = kh + (kt + 1) * (64 * 128);
      const unsigned short* vsrc = vh + (kt + 1) * 64;
#pragma unroll
      for (int i = 0; i < 4; ++i) {
        int c = w * 4 + i;
        int r = 4 * c + krow_off;
        int g = (lane & 15) ^ (r & 7);
        gl_lds16(ksrc + r * 128 + g * 8, &Ks[nb][c * 512]);
      }
#pragma unroll
      for (int i = 0; i < 4; ++i) {
        int r0 = (w * 4 + i) * 8;
        gl_lds16(vsrc + (long)(r0 + vrow_off) * T_SEQ + vg * 8, &Vts[nb][r0 * 64]);
      }
    }

    // S = Q K^T (16 x 64 per wave); K rows read with swizzled granule
    f32x4 sv[4];
#pragma unroll
    for (int n = 0; n < 4; ++n) { sv[n][0]=0.f; sv[n][1]=0.f; sv[n][2]=0.f; sv[n][3]=0.f; }
    __builtin_amdgcn_s_setprio(1);
#pragma unroll
    for (int ks = 0; ks < 4; ++ks)
#pragma unroll
      for (int n = 0; n < 4; ++n) {
        int R = n * 16 + fr;
        bf16x8 bk = *(const bf16x8*)&Ks[cur][R * 128 + (((ks * 4 + fq) ^ (fr & 7)) << 3)];
        sv[n] = __builtin_amdgcn_mfma_f32_16x16x32_bf16(aq[ks], bk, sv[n], 0, 0, 0);
      }
    __builtin_amdgcn_s_setprio(0);

    // scale + causal mask (only diagonal tile can mask)
#pragma unroll
    for (int n = 0; n < 4; ++n)
#pragma unroll
      for (int j3 = 0; j3 < 4; ++j3) {
        float s = sv[n][j3] * scale;
        if (kt == qb && (n * 16 + fr) > (w * 16 + fq * 4 + j3)) s = -__builtin_huge_valf();
        sv[n][j3] = s;
      }

    // row max over 64 cols: local over n, then 16-lane butterfly
    float pm[4];
#pragma unroll
    for (int j3 = 0; j3 < 4; ++j3)
      pm[j3] = fmaxf(fmaxf(sv[0][j3], sv[1][j3]), fmaxf(sv[2][j3], sv[3][j3]));
#pragma unroll
    for (int m = 1; m < 16; m <<= 1)
#pragma unroll
      for (int j3 = 0; j3 < 4; ++j3) pm[j3] = fmaxf(pm[j3], __shfl_xor(pm[j3], m, 64));

    float alpha[4];
#pragma unroll
    for (int j3 = 0; j3 < 4; ++j3) {
      float mn = fmaxf(mrow[j3], pm[j3]);
      alpha[j3] = __expf(mrow[j3] - mn);   // exp(-inf)=0 on first tile
      mrow[j3] = mn;
    }
    float rs[4] = {0.f, 0.f, 0.f, 0.f};
#pragma unroll
    for (int n = 0; n < 4; ++n)
#pragma unroll
      for (int j3 = 0; j3 < 4; ++j3) {
        float p = __expf(sv[n][j3] - mrow[j3]);
        sv[n][j3] = p;
        rs[j3] += p;
      }
#pragma unroll
    for (int m = 1; m < 16; m <<= 1)
#pragma unroll
      for (int j3 = 0; j3 < 4; ++j3) rs[j3] += __shfl_xor(rs[j3], m, 64);
#pragma unroll
    for (int j3 = 0; j3 < 4; ++j3) lrow[j3] = lrow[j3] * alpha[j3] + rs[j3];
#pragma unroll
    for (int n = 0; n < 8; ++n)
#pragma unroll
      for (int j3 = 0; j3 < 4; ++j3) acc[n][j3] *= alpha[j3];

    // P -> per-wave LDS (bf16), then read as PV A-fragments
    unsigned short* pl = &Ps[w][0];
#pragma unroll
    for (int n = 0; n < 4; ++n)
#pragma unroll
      for (int j3 = 0; j3 < 4; ++j3)
        pl[(fq * 4 + j3) * 72 + n * 16 + fr] = f2bf(sv[n][j3]);
    asm volatile("s_waitcnt lgkmcnt(0)" ::: "memory");
    __builtin_amdgcn_s_setprio(1);
#pragma unroll
    for (int ks = 0; ks < 2; ++ks) {
      bf16x8 pa = *(const bf16x8*)&pl[fr * 72 + ks * 32 + fq * 8];
#pragma unroll
      for (int n = 0; n < 8; ++n) {
        int R = n * 16 + fr;
        bf16x8 bv = *(const bf16x8*)&Vts[cur][R * 64 + (((ks * 4 + fq) ^ (fr & 7)) << 3)];
        acc[n] = __builtin_amdgcn_mfma_f32_16x16x32_bf16(pa, bv, acc[n], 0, 0, 0);
      }
    }
    __builtin_amdgcn_s_setprio(0);

    __syncthreads();   // vmcnt(0)+lgkmcnt(0)+barrier: next tile resident, this buf reusable
  }

  // epilogue: y[t][h*128+d] bf16
#pragma unroll
  for (int j3 = 0; j3 < 4; ++j3) {
    float inv = 1.0f / lrow[j3];
    int t = qb * 64 + w * 16 + fq * 4 + j3;
#pragma unroll
    for (int n = 0; n < 8; ++n)
      yb[(long)t * HS + h * 128 + n * 16 + fr] = f2bf(acc[n][j3] * inv);
  }
}

// ---------------- launch ----------------
extern "C" void kernel_launch(void* const* d_in, const int* in_sizes, int n_in,
                              void* d_out, int out_size, void* d_ws, size_t ws_size,
                              hipStream_t stream) {
  const float* x    = (const float*)d_in[0];
  const float* Wqkv = (const float*)d_in[1];
  const float* Wo_w = (const float*)d_in[2];
  const float* Wo_b = (const float*)d_in[3];
  float* out = (float*)d_out;
  char* ws = (char*)d_ws;

  unsigned short* xbf  = (unsigned short*)(ws + 0L);          //  8.0 MB
  unsigned short* wqbf = (unsigned short*)(ws + 8388608L);    // 24.0 MB
  unsigned short* wobf = (unsigned short*)(ws + 33554432L);   //  8.0 MB
  float*          qkv  = (float*)         (ws + 41943040L);   // 48.0 MB
  unsigned short* qb   = (unsigned short*)(ws + 92274688L);   //  8.0 MB
  unsigned short* kb   = (unsigned short*)(ws + 100663296L);  //  8.0 MB
  unsigned short* vt   = (unsigned short*)(ws + 109051904L);  //  8.0 MB
  unsigned short* yb   = (unsigned short*)(ws + 117440512L);  //  8.0 MB
  float*          cosd = (float*)         (ws + 125829120L);  //  0.5 MB
  float*          sind = (float*)         (ws + 126353408L);  //  0.5 MB

  cast_bf16_kernel<<<dim3(4194304 / 8 / 256), 256, 0, stream>>>(x, xbf, 4194304);
  cast_bf16_kernel<<<dim3(12582912 / 8 / 256), 256, 0, stream>>>(Wqkv, wqbf, 12582912);
  cast_bf16_kernel<<<dim3(4194304 / 8 / 256), 256, 0, stream>>>(Wo_w, wobf, 4194304);
  rope_table_kernel<<<dim3(512), 256, 0, stream>>>(cosd, sind);

  gemm_bt<0, 128><<<dim3(QKVN / 128, T_SEQ / 128), 256, 0, stream>>>(xbf, wqbf, qkv, nullptr,
                                                                     T_SEQ, QKVN, HS);
  normrope_qk<<<dim3(1024), 256, 0, stream>>>(qkv, cosd, sind, qb, kb);
  v_transpose<<<dim3(T_SEQ / 64, NH), 256, 0, stream>>>(qkv, vt);
  attn_kernel<<<dim3(512), 256, 0, stream>>>(qb, kb, vt, yb);
  gemm_bt<1, 64><<<dim3(HS / 64, T_SEQ / 128), 256, 0, stream>>>(yb, wobf, out, Wo_b,
                                                                 T_SEQ, HS, HS);
}

// Round 8
// 290.165 us; speedup vs baseline: 1.3691x; 1.0248x over previous
//
#include <hip/hip_runtime.h>
#include <hip/hip_bf16.h>
#include <stdint.h>

#define T_SEQ 2048
#define HS    2048
#define NH    16
#define DH    128
#define QKVN  (3*HS)

typedef __attribute__((ext_vector_type(8))) short          bf16x8;
typedef __attribute__((ext_vector_type(4))) float          f32x4;
typedef __attribute__((ext_vector_type(4))) unsigned short us4;
typedef __attribute__((ext_vector_type(8))) unsigned short us8;

// round-to-nearest-even f32 -> bf16 bits
__device__ __forceinline__ unsigned short f2bf(float x) {
  unsigned int u = __float_as_uint(x);
  return (unsigned short)((u + 0x7fffu + ((u >> 16) & 1u)) >> 16);
}

// async global->LDS, 16B per lane; lds base must be wave-uniform (lane i lands at base + i*16B)
__device__ __forceinline__ void gl_lds16(const void* g, void* l) {
  __builtin_amdgcn_global_load_lds((__attribute__((address_space(1))) void*)g,
                                   (__attribute__((address_space(3))) void*)l, 16, 0, 0);
}

// ---------------- elementwise cast f32 -> bf16 (vectorized 8/thread) ----------------
__global__ __launch_bounds__(256) void cast_bf16_kernel(const float* __restrict__ in,
                                                        unsigned short* __restrict__ out, int n) {
  int i = (blockIdx.x * 256 + threadIdx.x) * 8;
  if (i >= n) return;
  f32x4 a = *(const f32x4*)(in + i);
  f32x4 b = *(const f32x4*)(in + i + 4);
  us8 r;
#pragma unroll
  for (int j = 0; j < 4; ++j) { r[j] = f2bf(a[j]); r[j + 4] = f2bf(b[j]); }
  *(us8*)(out + i) = r;
}

// ---------------- RoPE cos/sin table [T][64] ----------------
__global__ __launch_bounds__(256) void rope_table_kernel(float* __restrict__ cosd,
                                                         float* __restrict__ sind) {
  int i = blockIdx.x * 256 + threadIdx.x;   // over T*64
  if (i >= T_SEQ * 64) return;
  int t = i >> 6, f = i & 63;
  float inv = expf(-9.210340371976184f * (float)f * (1.0f / 64.0f));
  float ang = (float)t * inv;
  float s, c;
  sincosf(ang, &s, &c);
  cosd[i] = c; sind[i] = s;
}

// ---------------- GEMM C[M][N] = A[M][K](bf16) * Bt[N][K](bf16)^T (+bias) ----------------
// 128xBN tile, BK=64, 256 threads (4 waves). LDS granule XOR-swizzle (g ^= row&7)
// applied via pre-swizzled global source (gl_lds dest linear) + same XOR on reads.
template <int BIAS, int BN>
__global__ __launch_bounds__(256, 4)
void gemm_bt(const unsigned short* __restrict__ A, const unsigned short* __restrict__ Bt,
             float* __restrict__ C, const float* __restrict__ bias, int M, int N, int K) {
  constexpr int FN = BN / 32;          // n-fragments per wave (128->4, 64->2)
  __shared__ unsigned short As[128 * 64];
  __shared__ unsigned short Bs[BN * 64];
  const int tid  = threadIdx.x;
  const int lane = tid & 63;
  const int w    = tid >> 6;
  const int fr   = lane & 15;   // fragment row/col
  const int fq   = lane >> 4;   // k-group
  const int bm   = blockIdx.y * 128;
  const int bn   = blockIdx.x * BN;
  const int wr   = (w >> 1) * 64;
  const int wc   = (w & 1) * (BN / 2);

  f32x4 acc[4][FN];
#pragma unroll
  for (int m = 0; m < 4; ++m)
#pragma unroll
    for (int n = 0; n < FN; ++n) { acc[m][n][0]=0.f; acc[m][n][1]=0.f; acc[m][n][2]=0.f; acc[m][n][3]=0.f; }

  const int srow = lane >> 3;
  const int sg   = (lane & 7) ^ srow;
  const unsigned short* Ag = A + (long)bm * K;
  const unsigned short* Bg = Bt + (long)bn * K;

  const int nk = K >> 6;
  for (int kt = 0; kt < nk; ++kt) {
    const int k0 = kt << 6;
    __syncthreads();               // previous compute done, LDS free
#pragma unroll
    for (int i = 0; i < 4; ++i) {
      int r = i * 32 + w * 8;      // wave-uniform chunk base row
      gl_lds16(Ag + (long)(r + srow) * K + k0 + sg * 8, &As[r * 64]);
    }
#pragma unroll
    for (int i = 0; i < BN / 32; ++i) {
      int r = i * 32 + w * 8;
      gl_lds16(Bg + (long)(r + srow) * K + k0 + sg * 8, &Bs[r * 64]);
    }
    __syncthreads();               // drains vmcnt(0): tiles resident
    __builtin_amdgcn_s_setprio(1);
#pragma unroll
    for (int ks = 0; ks < 2; ++ks) {
      bf16x8 af[4], bfr[FN];
#pragma unroll
      for (int m = 0; m < 4; ++m)
        af[m]  = *(const bf16x8*)&As[(wr + m * 16 + fr) * 64 + (((ks * 4 + fq) ^ (fr & 7)) << 3)];
#pragma unroll
      for (int n = 0; n < FN; ++n)
        bfr[n] = *(const bf16x8*)&Bs[(wc + n * 16 + fr) * 64 + (((ks * 4 + fq) ^ (fr & 7)) << 3)];
#pragma unroll
      for (int m = 0; m < 4; ++m)
#pragma unroll
        for (int n = 0; n < FN; ++n)
          acc[m][n] = __builtin_amdgcn_mfma_f32_16x16x32_bf16(af[m], bfr[n], acc[m][n], 0, 0, 0);
    }
    __builtin_amdgcn_s_setprio(0);
  }
  // epilogue: C/D layout col=lane&15, row=(lane>>4)*4+reg
#pragma unroll
  for (int m = 0; m < 4; ++m) {
    int row0 = bm + wr + m * 16 + fq * 4;
#pragma unroll
    for (int n = 0; n < FN; ++n) {
      int col = bn + wc + n * 16 + fr;
      float bv = BIAS ? bias[col] : 0.0f;
#pragma unroll
      for (int j = 0; j < 4; ++j)
        C[(long)(row0 + j) * N + col] = acc[m][n][j] + bv;
    }
  }
}

// ---------------- fused RMSNorm + RoPE for q,k; writes bf16 [h][t][d] ----------------
__global__ __launch_bounds__(256)
void normrope_qk(const float* __restrict__ qkv, const float* __restrict__ cosd,
                 const float* __restrict__ sind, unsigned short* __restrict__ qb,
                 unsigned short* __restrict__ kb) {
  const int wgl  = (blockIdx.x * 256 + threadIdx.x) >> 6;  // global wave id 0..4095
  const int lane = threadIdx.x & 63;
  for (int rr = wgl; rr < T_SEQ * 32; rr += 4096) {
    const int t = rr >> 5;
    const int y = rr & 31;               // 0..15 q heads, 16..31 k heads
    const float2 v = *(const float2*)(qkv + (long)t * QKVN + y * 128 + lane * 2);
    float ss = v.x * v.x + v.y * v.y;
#pragma unroll
    for (int m = 1; m < 64; m <<= 1) ss += __shfl_xor(ss, m, 64);
    const float r = rsqrtf(ss * (1.0f / 128.0f) + 1.1920928955078125e-07f);
    const float a = v.x * r, b = v.y * r;
    const float pa = __shfl_xor(a, 32, 64), pb = __shfl_xor(b, 32, 64);
    const float2 c2 = *(const float2*)(cosd + t * 64 + (lane & 31) * 2);
    const float2 s2 = *(const float2*)(sind + t * 64 + (lane & 31) * 2);
    float o0, o1;
    if (lane < 32) { o0 =  a * c2.x + pa * s2.x;  o1 =  b * c2.y + pb * s2.y; }
    else           { o0 = -pa * s2.x + a * c2.x;  o1 = -pb * s2.y + b * c2.y; }
    unsigned short* dst = (y >> 4) ? kb : qb;
    const unsigned int packed = (unsigned int)f2bf(o0) | ((unsigned int)f2bf(o1) << 16);
    *(unsigned int*)(dst + ((long)(y & 15) * T_SEQ + t) * 128 + lane * 2) = packed;
  }
}

// ---------------- V: cast + transpose to [h][d][t] bf16 ----------------
__global__ __launch_bounds__(256)
void v_transpose(const float* __restrict__ qkv, unsigned short* __restrict__ vt) {
  const int tb = blockIdx.x;   // 64-row t tile
  const int h  = blockIdx.y;
  __shared__ unsigned short vl[128][72];   // pad: row stride 144B (16B aligned)
  const int tid = threadIdx.x;
#pragma unroll
  for (int p = 0; p < 32; ++p) {
    int rr = p * 2 + (tid >> 7);
    int d  = tid & 127;
    float x = qkv[(long)(tb * 64 + rr) * QKVN + 2 * HS + h * 128 + d];
    vl[d][rr] = f2bf(x);
  }
  __syncthreads();
#pragma unroll
  for (int p = 0; p < 8; ++p) {
    int idx = (p * 256 + tid) * 4;   // elem in [128][64]
    int d = idx >> 6;
    int i = idx & 63;
    us4 val = *(const us4*)&vl[d][i];
    *(us4*)&vt[((long)h * DH + d) * T_SEQ + tb * 64 + i] = val;
  }
}

// ---------------- causal flash attention, in-block split-K ----------------
// 512 blocks (qb,h) balanced-paired; 512 threads = 8 waves = 2 groups of 4.
// Group g handles K-tiles kt = 2*it + g (even/odd split), own K/V dbuf + own
// online (m,l,acc). Loop count qb/2+1 identical for both groups (invalid last
// tile predicated off; mask value -1e30 keeps the math NaN-free). Final merge
// through LDS: group1 parks acc/m/l in its dead K/V buffers, group0 combines
// and writes. 8 waves/CU resident for the whole kernel (vs 4 before).
__global__ __launch_bounds__(512, 2)
void attn_kernel(const unsigned short* __restrict__ qg, const unsigned short* __restrict__ kg,
                 const unsigned short* __restrict__ vtg, unsigned short* __restrict__ yb) {
  const int bi = blockIdx.x;
  const int j  = (bi < 256) ? bi : bi - 256;
  const int h  = j & 15;
  const int q0 = j >> 4;                       // 0..15
  const int qb = (bi < 256) ? (31 - q0) : q0;  // first half long, second half short

  __shared__ unsigned short Ks[2][2][64 * 128];    // [group][buf] 64KB
  __shared__ unsigned short Vts[2][2][128 * 64];   // [group][buf] 64KB
  __shared__ unsigned short Ps[8][16 * 72];        // per-wave P tile 18KB

  const int tid = threadIdx.x, lane = tid & 63, w = tid >> 6;
  const int g = w >> 2, w4 = w & 3;
  const int fr = lane & 15, fq = lane >> 4;

  const unsigned short* qh = qg  + (long)h * T_SEQ * 128;
  const unsigned short* kh = kg  + (long)h * T_SEQ * 128;
  const unsigned short* vh = vtg + (long)h * 128 * T_SEQ;

  // K staging: instr i covers rows 4c..4c+3 (c=w4*4+i); lane row=4c+(lane>>4),
  // granule pos p=lane&15; pre-swizzled source granule = p ^ (row&7)
  const int krow_off = lane >> 4;
  // V staging: instr i covers rows r0..r0+7; lane row=r0+(lane>>3), pos=lane&7
  const int vrow_off = lane >> 3;
  const int vg       = (lane & 7) ^ vrow_off;

  // prologue: group g stages tile g (if valid) into buf 0
  if (g <= qb) {
#pragma unroll
    for (int i = 0; i < 4; ++i) {
      int c = w4 * 4 + i;
      int r = 4 * c + krow_off;
      int gr = (lane & 15) ^ (r & 7);
      gl_lds16(kh + (long)g * 8192 + r * 128 + gr * 8, &Ks[g][0][c * 512]);
    }
#pragma unroll
    for (int i = 0; i < 4; ++i) {
      int r0 = (w4 * 4 + i) * 8;
      gl_lds16(vh + (long)(r0 + vrow_off) * T_SEQ + g * 64 + vg * 8, &Vts[g][0][r0 * 64]);
    }
  }

  // Q fragments straight from global (both groups load the same rows)
  bf16x8 aq[4];
  {
    const unsigned short* qrow = qh + (long)(qb * 64 + w4 * 16 + fr) * 128;
#pragma unroll
    for (int ks = 0; ks < 4; ++ks)
      aq[ks] = *(const bf16x8*)(qrow + ks * 32 + fq * 8);
  }

  f32x4 acc[8];
#pragma unroll
  for (int n = 0; n < 8; ++n) { acc[n][0]=0.f; acc[n][1]=0.f; acc[n][2]=0.f; acc[n][3]=0.f; }
  float mrow[4], lrow[4];
#pragma unroll
  for (int j2 = 0; j2 < 4; ++j2) { mrow[j2] = -1e30f; lrow[j2] = 0.f; }

  const float scale = 0.08838834764831845f;   // 1/sqrt(128)
  const int nt = (qb >> 1) + 1;

  __syncthreads();   // tile-0 resident (vmcnt drained by barrier semantics)

  for (int it = 0; it < nt; ++it) {
    const int cur = it & 1;
    const int kt  = 2 * it + g;

    // prefetch tile kt+2 into alt buffer
    if (kt + 2 <= qb) {
      const int nb = cur ^ 1;
      const unsigned short* ksrc = kh + (long)(kt + 2) * 8192;
#pragma unroll
      for (int i = 0; i < 4; ++i) {
        int c = w4 * 4 + i;
        int r = 4 * c + krow_off;
        int gr = (lane & 15) ^ (r & 7);
        gl_lds16(ksrc + r * 128 + gr * 8, &Ks[g][nb][c * 512]);
      }
#pragma unroll
      for (int i = 0; i < 4; ++i) {
        int r0 = (w4 * 4 + i) * 8;
        gl_lds16(vh + (long)(r0 + vrow_off) * T_SEQ + (kt + 2) * 64 + vg * 8, &Vts[g][nb][r0 * 64]);
      }
    }

    if (kt <= qb) {
      // S = Q K^T (16 x 64 per wave)
      f32x4 sv[4];
#pragma unroll
      for (int n = 0; n < 4; ++n) { sv[n][0]=0.f; sv[n][1]=0.f; sv[n][2]=0.f; sv[n][3]=0.f; }
      __builtin_amdgcn_s_setprio(1);
#pragma unroll
      for (int ks = 0; ks < 4; ++ks)
#pragma unroll
        for (int n = 0; n < 4; ++n) {
          int R = n * 16 + fr;
          bf16x8 bk = *(const bf16x8*)&Ks[g][cur][R * 128 + (((ks * 4 + fq) ^ (fr & 7)) << 3)];
          sv[n] = __builtin_amdgcn_mfma_f32_16x16x32_bf16(aq[ks], bk, sv[n], 0, 0, 0);
        }
      __builtin_amdgcn_s_setprio(0);

      // scale + causal mask (diagonal tile only)
#pragma unroll
      for (int n = 0; n < 4; ++n)
#pragma unroll
        for (int j3 = 0; j3 < 4; ++j3) {
          float s = sv[n][j3] * scale;
          if (kt == qb && (n * 16 + fr) > (w4 * 16 + fq * 4 + j3)) s = -1e30f;
          sv[n][j3] = s;
        }

      // row max over 64 cols
      float pm[4];
#pragma unroll
      for (int j3 = 0; j3 < 4; ++j3)
        pm[j3] = fmaxf(fmaxf(sv[0][j3], sv[1][j3]), fmaxf(sv[2][j3], sv[3][j3]));
#pragma unroll
      for (int m = 1; m < 16; m <<= 1)
#pragma unroll
        for (int j3 = 0; j3 < 4; ++j3) pm[j3] = fmaxf(pm[j3], __shfl_xor(pm[j3], m, 64));

      float alpha[4];
#pragma unroll
      for (int j3 = 0; j3 < 4; ++j3) {
        float mn = fmaxf(mrow[j3], pm[j3]);
        alpha[j3] = __expf(mrow[j3] - mn);
        mrow[j3] = mn;
      }
      float rs[4] = {0.f, 0.f, 0.f, 0.f};
#pragma unroll
      for (int n = 0; n < 4; ++n)
#pragma unroll
        for (int j3 = 0; j3 < 4; ++j3) {
          float p = __expf(sv[n][j3] - mrow[j3]);
          sv[n][j3] = p;
          rs[j3] += p;
        }
#pragma unroll
      for (int m = 1; m < 16; m <<= 1)
#pragma unroll
        for (int j3 = 0; j3 < 4; ++j3) rs[j3] += __shfl_xor(rs[j3], m, 64);
#pragma unroll
      for (int j3 = 0; j3 < 4; ++j3) lrow[j3] = lrow[j3] * alpha[j3] + rs[j3];
#pragma unroll
      for (int n = 0; n < 8; ++n)
#pragma unroll
        for (int j3 = 0; j3 < 4; ++j3) acc[n][j3] *= alpha[j3];

      // P -> per-wave LDS (bf16), then PV
      unsigned short* pl = &Ps[w][0];
#pragma unroll
      for (int n = 0; n < 4; ++n)
#pragma unroll
        for (int j3 = 0; j3 < 4; ++j3)
          pl[(fq * 4 + j3) * 72 + n * 16 + fr] = f2bf(sv[n][j3]);
      asm volatile("s_waitcnt lgkmcnt(0)" ::: "memory");
      __builtin_amdgcn_s_setprio(1);
#pragma unroll
      for (int ks = 0; ks < 2; ++ks) {
        bf16x8 pa = *(const bf16x8*)&pl[fr * 72 + ks * 32 + fq * 8];
#pragma unroll
        for (int n = 0; n < 8; ++n) {
          int R = n * 16 + fr;
          bf16x8 bv = *(const bf16x8*)&Vts[g][cur][R * 64 + (((ks * 4 + fq) ^ (fr & 7)) << 3)];
          acc[n] = __builtin_amdgcn_mfma_f32_16x16x32_bf16(pa, bv, acc[n], 0, 0, 0);
        }
      }
      __builtin_amdgcn_s_setprio(0);
    }

    __syncthreads();   // both groups: next tile resident, buffers reusable
  }

  // ---- merge group1 into group0 via LDS (overlay group1's dead K/V buffers)
  float* accL = (float*)&Ks[1][0][0];    // 64 x 128 f32 = 32KB
  float* mlL  = (float*)&Vts[1][0][0];   // m[64], l[64]
  if (g == 1) {
#pragma unroll
    for (int j3 = 0; j3 < 4; ++j3) {
      int row = w4 * 16 + fq * 4 + j3;
#pragma unroll
      for (int n = 0; n < 8; ++n)
        accL[row * 128 + n * 16 + fr] = acc[n][j3];
      if (fr == 0) { mlL[row] = mrow[j3]; mlL[64 + row] = lrow[j3]; }
    }
  }
  __syncthreads();
  if (g == 0) {
#pragma unroll
    for (int j3 = 0; j3 < 4; ++j3) {
      int row = w4 * 16 + fq * 4 + j3;
      float m1 = mlL[row], l1 = mlL[64 + row];
      float m  = fmaxf(mrow[j3], m1);
      float a0 = __expf(mrow[j3] - m), a1 = __expf(m1 - m);
      float inv = 1.0f / (lrow[j3] * a0 + l1 * a1);
      int t = qb * 64 + row;
#pragma unroll
      for (int n = 0; n < 8; ++n) {
        float v = (acc[n][j3] * a0 + accL[row * 128 + n * 16 + fr] * a1) * inv;
        yb[(long)t * HS + h * 128 + n * 16 + fr] = f2bf(v);
      }
    }
  }
}

// ---------------- launch ----------------
extern "C" void kernel_launch(void* const* d_in, const int* in_sizes, int n_in,
                              void* d_out, int out_size, void* d_ws, size_t ws_size,
                              hipStream_t stream) {
  const float* x    = (const float*)d_in[0];
  const float* Wqkv = (const float*)d_in[1];
  const float* Wo_w = (const float*)d_in[2];
  const float* Wo_b = (const float*)d_in[3];
  float* out = (float*)d_out;
  char* ws = (char*)d_ws;

  unsigned short* xbf  = (unsigned short*)(ws + 0L);          //  8.0 MB
  unsigned short* wqbf = (unsigned short*)(ws + 8388608L);    // 24.0 MB
  unsigned short* wobf = (unsigned short*)(ws + 33554432L);   //  8.0 MB
  float*          qkv  = (float*)         (ws + 41943040L);   // 48.0 MB
  unsigned short* qb   = (unsigned short*)(ws + 92274688L);   //  8.0 MB
  unsigned short* kb   = (unsigned short*)(ws + 100663296L);  //  8.0 MB
  unsigned short* vt   = (unsigned short*)(ws + 109051904L);  //  8.0 MB
  unsigned short* yb   = (unsigned short*)(ws + 117440512L);  //  8.0 MB
  float*          cosd = (float*)         (ws + 125829120L);  //  0.5 MB
  float*          sind = (float*)         (ws + 126353408L);  //  0.5 MB

  cast_bf16_kernel<<<dim3(4194304 / 8 / 256), 256, 0, stream>>>(x, xbf, 4194304);
  cast_bf16_kernel<<<dim3(12582912 / 8 / 256), 256, 0, stream>>>(Wqkv, wqbf, 12582912);
  cast_bf16_kernel<<<dim3(4194304 / 8 / 256), 256, 0, stream>>>(Wo_w, wobf, 4194304);
  rope_table_kernel<<<dim3(512), 256, 0, stream>>>(cosd, sind);

  gemm_bt<0, 128><<<dim3(QKVN / 128, T_SEQ / 128), 256, 0, stream>>>(xbf, wqbf, qkv, nullptr,
                                                                     T_SEQ, QKVN, HS);
  normrope_qk<<<dim3(1024), 256, 0, stream>>>(qkv, cosd, sind, qb, kb);
  v_transpose<<<dim3(T_SEQ / 64, NH), 256, 0, stream>>>(qkv, vt);
  attn_kernel<<<dim3(512), 512, 0, stream>>>(qb, kb, vt, yb);
  gemm_bt<1, 64><<<dim3(HS / 64, T_SEQ / 128), 256, 0, stream>>>(yb, wobf, out, Wo_b,
                                                                 T_SEQ, HS, HS);
}

// Round 9
// 289.097 us; speedup vs baseline: 1.3742x; 1.0037x over previous
//
#include <hip/hip_runtime.h>
#include <hip/hip_bf16.h>
#include <stdint.h>

#define T_SEQ 2048
#define HS    2048
#define NH    16
#define DH    128
#define QKVN  (3*HS)

typedef __attribute__((ext_vector_type(8))) short          bf16x8;
typedef __attribute__((ext_vector_type(4))) float          f32x4;
typedef __attribute__((ext_vector_type(4))) unsigned short us4;
typedef __attribute__((ext_vector_type(8))) unsigned short us8;

// round-to-nearest-even f32 -> bf16 bits
__device__ __forceinline__ unsigned short f2bf(float x) {
  unsigned int u = __float_as_uint(x);
  return (unsigned short)((u + 0x7fffu + ((u >> 16) & 1u)) >> 16);
}

// async global->LDS, 16B per lane; lds base must be wave-uniform (lane i lands at base + i*16B)
__device__ __forceinline__ void gl_lds16(const void* g, void* l) {
  __builtin_amdgcn_global_load_lds((__attribute__((address_space(1))) void*)g,
                                   (__attribute__((address_space(3))) void*)l, 16, 0, 0);
}

// ---------------- elementwise cast f32 -> bf16 (vectorized 8/thread) ----------------
__global__ __launch_bounds__(256) void cast_bf16_kernel(const float* __restrict__ in,
                                                        unsigned short* __restrict__ out, int n) {
  int i = (blockIdx.x * 256 + threadIdx.x) * 8;
  if (i >= n) return;
  f32x4 a = *(const f32x4*)(in + i);
  f32x4 b = *(const f32x4*)(in + i + 4);
  us8 r;
#pragma unroll
  for (int j = 0; j < 4; ++j) { r[j] = f2bf(a[j]); r[j + 4] = f2bf(b[j]); }
  *(us8*)(out + i) = r;
}

// ---------------- RoPE cos/sin table [T][64] ----------------
__global__ __launch_bounds__(256) void rope_table_kernel(float* __restrict__ cosd,
                                                         float* __restrict__ sind) {
  int i = blockIdx.x * 256 + threadIdx.x;   // over T*64
  if (i >= T_SEQ * 64) return;
  int t = i >> 6, f = i & 63;
  float inv = expf(-9.210340371976184f * (float)f * (1.0f / 64.0f));
  float ang = (float)t * inv;
  float s, c;
  sincosf(ang, &s, &c);
  cosd[i] = c; sind[i] = s;
}

// ---------------- GEMM C[M][N] = A[M][K](bf16) * Bt[N][K](bf16)^T (+bias) ----------------
template <int BIAS, int BN>
__global__ __launch_bounds__(256, 4)
void gemm_bt(const unsigned short* __restrict__ A, const unsigned short* __restrict__ Bt,
             float* __restrict__ C, const float* __restrict__ bias, int M, int N, int K) {
  constexpr int FN = BN / 32;          // n-fragments per wave (128->4, 64->2)
  __shared__ unsigned short As[128 * 64];
  __shared__ unsigned short Bs[BN * 64];
  const int tid  = threadIdx.x;
  const int lane = tid & 63;
  const int w    = tid >> 6;
  const int fr   = lane & 15;   // fragment row/col
  const int fq   = lane >> 4;   // k-group
  const int bm   = blockIdx.y * 128;
  const int bn   = blockIdx.x * BN;
  const int wr   = (w >> 1) * 64;
  const int wc   = (w & 1) * (BN / 2);

  f32x4 acc[4][FN];
#pragma unroll
  for (int m = 0; m < 4; ++m)
#pragma unroll
    for (int n = 0; n < FN; ++n) { acc[m][n][0]=0.f; acc[m][n][1]=0.f; acc[m][n][2]=0.f; acc[m][n][3]=0.f; }

  const int srow = lane >> 3;
  const int sg   = (lane & 7) ^ srow;
  const unsigned short* Ag = A + (long)bm * K;
  const unsigned short* Bg = Bt + (long)bn * K;

  const int nk = K >> 6;
  for (int kt = 0; kt < nk; ++kt) {
    const int k0 = kt << 6;
    __syncthreads();               // previous compute done, LDS free
#pragma unroll
    for (int i = 0; i < 4; ++i) {
      int r = i * 32 + w * 8;      // wave-uniform chunk base row
      gl_lds16(Ag + (long)(r + srow) * K + k0 + sg * 8, &As[r * 64]);
    }
#pragma unroll
    for (int i = 0; i < BN / 32; ++i) {
      int r = i * 32 + w * 8;
      gl_lds16(Bg + (long)(r + srow) * K + k0 + sg * 8, &Bs[r * 64]);
    }
    __syncthreads();               // drains vmcnt(0): tiles resident
    __builtin_amdgcn_s_setprio(1);
#pragma unroll
    for (int ks = 0; ks < 2; ++ks) {
      bf16x8 af[4], bfr[FN];
#pragma unroll
      for (int m = 0; m < 4; ++m)
        af[m]  = *(const bf16x8*)&As[(wr + m * 16 + fr) * 64 + (((ks * 4 + fq) ^ (fr & 7)) << 3)];
#pragma unroll
      for (int n = 0; n < FN; ++n)
        bfr[n] = *(const bf16x8*)&Bs[(wc + n * 16 + fr) * 64 + (((ks * 4 + fq) ^ (fr & 7)) << 3)];
#pragma unroll
      for (int m = 0; m < 4; ++m)
#pragma unroll
        for (int n = 0; n < FN; ++n)
          acc[m][n] = __builtin_amdgcn_mfma_f32_16x16x32_bf16(af[m], bfr[n], acc[m][n], 0, 0, 0);
    }
    __builtin_amdgcn_s_setprio(0);
  }
  // epilogue: C/D layout col=lane&15, row=(lane>>4)*4+reg
#pragma unroll
  for (int m = 0; m < 4; ++m) {
    int row0 = bm + wr + m * 16 + fq * 4;
#pragma unroll
    for (int n = 0; n < FN; ++n) {
      int col = bn + wc + n * 16 + fr;
      float bv = BIAS ? bias[col] : 0.0f;
#pragma unroll
      for (int j = 0; j < 4; ++j)
        C[(long)(row0 + j) * N + col] = acc[m][n][j] + bv;
    }
  }
}

// ---------------- fused RMSNorm + RoPE for q,k; writes bf16 [h][t][d] ----------------
__global__ __launch_bounds__(256)
void normrope_qk(const float* __restrict__ qkv, const float* __restrict__ cosd,
                 const float* __restrict__ sind, unsigned short* __restrict__ qb,
                 unsigned short* __restrict__ kb) {
  const int wgl  = (blockIdx.x * 256 + threadIdx.x) >> 6;  // global wave id 0..4095
  const int lane = threadIdx.x & 63;
  for (int rr = wgl; rr < T_SEQ * 32; rr += 4096) {
    const int t = rr >> 5;
    const int y = rr & 31;               // 0..15 q heads, 16..31 k heads
    const float2 v = *(const float2*)(qkv + (long)t * QKVN + y * 128 + lane * 2);
    float ss = v.x * v.x + v.y * v.y;
#pragma unroll
    for (int m = 1; m < 64; m <<= 1) ss += __shfl_xor(ss, m, 64);
    const float r = rsqrtf(ss * (1.0f / 128.0f) + 1.1920928955078125e-07f);
    const float a = v.x * r, b = v.y * r;
    const float pa = __shfl_xor(a, 32, 64), pb = __shfl_xor(b, 32, 64);
    const float2 c2 = *(const float2*)(cosd + t * 64 + (lane & 31) * 2);
    const float2 s2 = *(const float2*)(sind + t * 64 + (lane & 31) * 2);
    float o0, o1;
    if (lane < 32) { o0 =  a * c2.x + pa * s2.x;  o1 =  b * c2.y + pb * s2.y; }
    else           { o0 = -pa * s2.x + a * c2.x;  o1 = -pb * s2.y + b * c2.y; }
    unsigned short* dst = (y >> 4) ? kb : qb;
    const unsigned int packed = (unsigned int)f2bf(o0) | ((unsigned int)f2bf(o1) << 16);
    *(unsigned int*)(dst + ((long)(y & 15) * T_SEQ + t) * 128 + lane * 2) = packed;
  }
}

// ---------------- V: cast + transpose to [h][d][t] bf16 ----------------
__global__ __launch_bounds__(256)
void v_transpose(const float* __restrict__ qkv, unsigned short* __restrict__ vt) {
  const int tb = blockIdx.x;   // 64-row t tile
  const int h  = blockIdx.y;
  __shared__ unsigned short vl[128][72];   // pad: row stride 144B (16B aligned)
  const int tid = threadIdx.x;
#pragma unroll
  for (int p = 0; p < 32; ++p) {
    int rr = p * 2 + (tid >> 7);
    int d  = tid & 127;
    float x = qkv[(long)(tb * 64 + rr) * QKVN + 2 * HS + h * 128 + d];
    vl[d][rr] = f2bf(x);
  }
  __syncthreads();
#pragma unroll
  for (int p = 0; p < 8; ++p) {
    int idx = (p * 256 + tid) * 4;   // elem in [128][64]
    int d = idx >> 6;
    int i = idx & 63;
    us4 val = *(const us4*)&vl[d][i];
    *(us4*)&vt[((long)h * DH + d) * T_SEQ + tb * 64 + i] = val;
  }
}

// ---------------- causal flash attention, cross-block split-K ----------------
// 1024 blocks x 256 thr (4 waves). Each (qb,h) handled by TWO blocks:
//   p0: kt in [0, qb/2], p1: kt in [qb/2+1, qb]  (p1 empty only for qb=0).
// Block map (i = blockIdx.x, q0=(i&255)>>4, h=i&15, quarter=i>>8):
//   Q0:(31-q0,p0) Q1:(31-q0,p1) Q2:(q0,p0) Q3:(q0,p1) -> heavy blocks first,
//   per-CU cost sums ~33 tiles over 2 resident slots (~17 serial tile-times).
// LDS 73KB double-buffered -> 2 blocks/CU, 8 waves/CU sustained.
// Partials (acc f32[64][128], m/l f32[2][64]) -> ws; merged by attn_combine.
__global__ __launch_bounds__(256, 2)
void attn_kernel(const unsigned short* __restrict__ qg, const unsigned short* __restrict__ kg,
                 const unsigned short* __restrict__ vtg, float* __restrict__ accG,
                 float* __restrict__ mlG) {
  const int bi = blockIdx.x;
  const int q0 = (bi & 255) >> 4;
  const int h  = bi & 15;
  const int quarter = bi >> 8;
  const int qb = (quarter < 2) ? (31 - q0) : q0;
  const int p  = quarter & 1;
  const int slot = (qb * 16 + h) * 2 + p;

  const int kt0 = p ? ((qb >> 1) + 1) : 0;
  const int kte = p ? qb : (qb >> 1);

  const int tid = threadIdx.x, lane = tid & 63, w = tid >> 6;
  const int fr = lane & 15, fq = lane >> 4;

  float* accO = accG + (long)slot * 8192;
  float* mlO  = mlG + slot * 128;

  if (kt0 > kte) {   // empty K-range (qb==0, p1): neutral stats only (uniform branch)
#pragma unroll
    for (int j3 = 0; j3 < 4; ++j3) {
      int row = w * 16 + fq * 4 + j3;
      if (fr == 0) { mlO[row] = -1e30f; mlO[64 + row] = 0.f; }
    }
    return;
  }

  __shared__ unsigned short Ks[2][64 * 128];
  __shared__ unsigned short Vts[2][128 * 64];
  __shared__ unsigned short Ps[4][16 * 72];

  const unsigned short* qh = qg  + (long)h * T_SEQ * 128;
  const unsigned short* kh = kg  + (long)h * T_SEQ * 128;
  const unsigned short* vh = vtg + (long)h * 128 * T_SEQ;

  const int krow_off = lane >> 4;
  const int vrow_off = lane >> 3;
  const int vg       = (lane & 7) ^ vrow_off;

  // prologue: stage tile kt0 -> buf 0
  {
    const unsigned short* ksrc = kh + (long)kt0 * 8192;
#pragma unroll
    for (int i = 0; i < 4; ++i) {
      int c = w * 4 + i;
      int r = 4 * c + krow_off;
      int gr = (lane & 15) ^ (r & 7);
      gl_lds16(ksrc + r * 128 + gr * 8, &Ks[0][c * 512]);
    }
#pragma unroll
    for (int i = 0; i < 4; ++i) {
      int r0 = (w * 4 + i) * 8;
      gl_lds16(vh + (long)(r0 + vrow_off) * T_SEQ + kt0 * 64 + vg * 8, &Vts[0][r0 * 64]);
    }
  }

  // Q fragments straight from global
  bf16x8 aq[4];
  {
    const unsigned short* qrow = qh + (long)(qb * 64 + w * 16 + fr) * 128;
#pragma unroll
    for (int ks = 0; ks < 4; ++ks)
      aq[ks] = *(const bf16x8*)(qrow + ks * 32 + fq * 8);
  }

  f32x4 acc[8];
#pragma unroll
  for (int n = 0; n < 8; ++n) { acc[n][0]=0.f; acc[n][1]=0.f; acc[n][2]=0.f; acc[n][3]=0.f; }
  float mrow[4], lrow[4];
#pragma unroll
  for (int j2 = 0; j2 < 4; ++j2) { mrow[j2] = -1e30f; lrow[j2] = 0.f; }

  const float scale = 0.08838834764831845f;   // 1/sqrt(128)

  __syncthreads();   // tile kt0 resident

  for (int kt = kt0; kt <= kte; ++kt) {
    const int cur = (kt - kt0) & 1;

    // prefetch tile kt+1 into alt buffer
    if (kt < kte) {
      const int nb = cur ^ 1;
      const unsigned short* ksrc = kh + (long)(kt + 1) * 8192;
#pragma unroll
      for (int i = 0; i < 4; ++i) {
        int c = w * 4 + i;
        int r = 4 * c + krow_off;
        int gr = (lane & 15) ^ (r & 7);
        gl_lds16(ksrc + r * 128 + gr * 8, &Ks[nb][c * 512]);
      }
#pragma unroll
      for (int i = 0; i < 4; ++i) {
        int r0 = (w * 4 + i) * 8;
        gl_lds16(vh + (long)(r0 + vrow_off) * T_SEQ + (kt + 1) * 64 + vg * 8, &Vts[nb][r0 * 64]);
      }
    }

    // S = Q K^T (16 x 64 per wave)
    f32x4 sv[4];
#pragma unroll
    for (int n = 0; n < 4; ++n) { sv[n][0]=0.f; sv[n][1]=0.f; sv[n][2]=0.f; sv[n][3]=0.f; }
    __builtin_amdgcn_s_setprio(1);
#pragma unroll
    for (int ks = 0; ks < 4; ++ks)
#pragma unroll
      for (int n = 0; n < 4; ++n) {
        int R = n * 16 + fr;
        bf16x8 bk = *(const bf16x8*)&Ks[cur][R * 128 + (((ks * 4 + fq) ^ (fr & 7)) << 3)];
        sv[n] = __builtin_amdgcn_mfma_f32_16x16x32_bf16(aq[ks], bk, sv[n], 0, 0, 0);
      }
    __builtin_amdgcn_s_setprio(0);

    // scale + causal mask (diagonal tile only)
#pragma unroll
    for (int n = 0; n < 4; ++n)
#pragma unroll
      for (int j3 = 0; j3 < 4; ++j3) {
        float s = sv[n][j3] * scale;
        if (kt == qb && (n * 16 + fr) > (w * 16 + fq * 4 + j3)) s = -1e30f;
        sv[n][j3] = s;
      }

    // row max over 64 cols
    float pm[4];
#pragma unroll
    for (int j3 = 0; j3 < 4; ++j3)
      pm[j3] = fmaxf(fmaxf(sv[0][j3], sv[1][j3]), fmaxf(sv[2][j3], sv[3][j3]));
#pragma unroll
    for (int m = 1; m < 16; m <<= 1)
#pragma unroll
      for (int j3 = 0; j3 < 4; ++j3) pm[j3] = fmaxf(pm[j3], __shfl_xor(pm[j3], m, 64));

    float alpha[4];
#pragma unroll
    for (int j3 = 0; j3 < 4; ++j3) {
      float mn = fmaxf(mrow[j3], pm[j3]);
      alpha[j3] = __expf(mrow[j3] - mn);
      mrow[j3] = mn;
    }
    float rs[4] = {0.f, 0.f, 0.f, 0.f};
#pragma unroll
    for (int n = 0; n < 4; ++n)
#pragma unroll
      for (int j3 = 0; j3 < 4; ++j3) {
        float pval = __expf(sv[n][j3] - mrow[j3]);
        sv[n][j3] = pval;
        rs[j3] += pval;
      }
#pragma unroll
    for (int m = 1; m < 16; m <<= 1)
#pragma unroll
      for (int j3 = 0; j3 < 4; ++j3) rs[j3] += __shfl_xor(rs[j3], m, 64);
#pragma unroll
    for (int j3 = 0; j3 < 4; ++j3) lrow[j3] = lrow[j3] * alpha[j3] + rs[j3];
#pragma unroll
    for (int n = 0; n < 8; ++n)
#pragma unroll
      for (int j3 = 0; j3 < 4; ++j3) acc[n][j3] *= alpha[j3];

    // P -> per-wave LDS (bf16), then PV
    unsigned short* pl = &Ps[w][0];
#pragma unroll
    for (int n = 0; n < 4; ++n)
#pragma unroll
      for (int j3 = 0; j3 < 4; ++j3)
        pl[(fq * 4 + j3) * 72 + n * 16 + fr] = f2bf(sv[n][j3]);
    asm volatile("s_waitcnt lgkmcnt(0)" ::: "memory");
    __builtin_amdgcn_s_setprio(1);
#pragma unroll
    for (int ks = 0; ks < 2; ++ks) {
      bf16x8 pa = *(const bf16x8*)&pl[fr * 72 + ks * 32 + fq * 8];
#pragma unroll
      for (int n = 0; n < 8; ++n) {
        int R = n * 16 + fr;
        bf16x8 bv = *(const bf16x8*)&Vts[cur][R * 64 + (((ks * 4 + fq) ^ (fr & 7)) << 3)];
        acc[n] = __builtin_amdgcn_mfma_f32_16x16x32_bf16(pa, bv, acc[n], 0, 0, 0);
      }
    }
    __builtin_amdgcn_s_setprio(0);

    __syncthreads();   // next tile resident, buffers reusable
  }

  // write partials
#pragma unroll
  for (int j3 = 0; j3 < 4; ++j3) {
    int row = w * 16 + fq * 4 + j3;
#pragma unroll
    for (int n = 0; n < 8; ++n)
      accO[row * 128 + n * 16 + fr] = acc[n][j3];
    if (fr == 0) { mlO[row] = mrow[j3]; mlO[64 + row] = lrow[j3]; }
  }
}

// ---------------- combine split-K partials -> yb bf16 ----------------
// 512 blocks (qb*16+h), 256 thr; merges two partials with online-softmax algebra.
__global__ __launch_bounds__(256)
void attn_combine(const float* __restrict__ accG, const float* __restrict__ mlG,
                  unsigned short* __restrict__ yb) {
  const int j = blockIdx.x;
  const int qb = j >> 4, h = j & 15;
  const float* a0 = accG + (long)(j * 2 + 0) * 8192;
  const float* a1 = accG + (long)(j * 2 + 1) * 8192;
  const float* ml0 = mlG + (j * 2 + 0) * 128;
  const float* ml1 = mlG + (j * 2 + 1) * 128;
  const int tid = threadIdx.x;
#pragma unroll
  for (int e = 0; e < 8; ++e) {
    int idx = e * 256 + tid;            // 0..2047, covers [64][32] f32x4 slots
    int row = idx >> 5;
    int c4  = (idx & 31) * 4;
    float m0 = ml0[row], l0 = ml0[64 + row];
    float m1 = ml1[row], l1 = ml1[64 + row];
    float m  = fmaxf(m0, m1);
    float w0 = __expf(m0 - m), w1 = __expf(m1 - m);
    float inv = 1.0f / (l0 * w0 + l1 * w1);
    f32x4 A = *(const f32x4*)(a0 + row * 128 + c4);
    f32x4 B = *(const f32x4*)(a1 + row * 128 + c4);
    us4 o;
#pragma unroll
    for (int q = 0; q < 4; ++q)
      o[q] = f2bf((A[q] * w0 + B[q] * w1) * inv);
    *(us4*)(yb + (long)(qb * 64 + row) * HS + h * 128 + c4) = o;
  }
}

// ---------------- launch ----------------
extern "C" void kernel_launch(void* const* d_in, const int* in_sizes, int n_in,
                              void* d_out, int out_size, void* d_ws, size_t ws_size,
                              hipStream_t stream) {
  const float* x    = (const float*)d_in[0];
  const float* Wqkv = (const float*)d_in[1];
  const float* Wo_w = (const float*)d_in[2];
  const float* Wo_b = (const float*)d_in[3];
  float* out = (float*)d_out;
  char* ws = (char*)d_ws;

  unsigned short* xbf  = (unsigned short*)(ws + 0L);          //  8.0 MB
  unsigned short* wqbf = (unsigned short*)(ws + 8388608L);    // 24.0 MB
  unsigned short* wobf = (unsigned short*)(ws + 33554432L);   //  8.0 MB
  float*          qkv  = (float*)         (ws + 41943040L);   // 48.0 MB
  unsigned short* qb   = (unsigned short*)(ws + 92274688L);   //  8.0 MB
  unsigned short* kb   = (unsigned short*)(ws + 100663296L);  //  8.0 MB
  unsigned short* vt   = (unsigned short*)(ws + 109051904L);  //  8.0 MB
  unsigned short* yb   = (unsigned short*)(ws + 117440512L);  //  8.0 MB
  float*          cosd = (float*)         (ws + 125829120L);  //  0.5 MB
  float*          sind = (float*)         (ws + 126353408L);  //  0.5 MB
  // overlays (dead by the time attn runs): acc partials over xbf+wqbf, m/l over qkv
  float*          accG = (float*)         (ws + 0L);          // 32.0 MB (1024 x 64 x 128 f32)
  float*          mlG  = (float*)         (ws + 41943040L);   //  0.5 MB (1024 x 128 f32)

  cast_bf16_kernel<<<dim3(4194304 / 8 / 256), 256, 0, stream>>>(x, xbf, 4194304);
  cast_bf16_kernel<<<dim3(12582912 / 8 / 256), 256, 0, stream>>>(Wqkv, wqbf, 12582912);
  cast_bf16_kernel<<<dim3(4194304 / 8 / 256), 256, 0, stream>>>(Wo_w, wobf, 4194304);
  rope_table_kernel<<<dim3(512), 256, 0, stream>>>(cosd, sind);

  gemm_bt<0, 128><<<dim3(QKVN / 128, T_SEQ / 128), 256, 0, stream>>>(xbf, wqbf, qkv, nullptr,
                                                                     T_SEQ, QKVN, HS);
  normrope_qk<<<dim3(1024), 256, 0, stream>>>(qkv, cosd, sind, qb, kb);
  v_transpose<<<dim3(T_SEQ / 64, NH), 256, 0, stream>>>(qkv, vt);
  attn_kernel<<<dim3(1024), 256, 0, stream>>>(qb, kb, vt, accG, mlG);
  attn_combine<<<dim3(512), 256, 0, stream>>>(accG, mlG, yb);
  gemm_bt<1, 64><<<dim3(HS / 64, T_SEQ / 128), 256, 0, stream>>>(yb, wobf, out, Wo_b,
                                                                 T_SEQ, HS, HS);
}